// Round 7
// baseline (274.326 us; speedup 1.0000x reference)
//
#include <hip/hip_runtime.h>
#include <hip/hip_bf16.h>

// N=25000, E=400000 (+N self loops), F_IN=64, HID=128, HEADS=4, OUT=256
// bf16 MFMA GEMMs (embed GEMM fused into layer-1 GEMM via LDS round-trip);
// node-feature gather operands stored fp8(e4m3); alpha dots fused into GEMM
// epilogues (f32-exact); edge logits computed on the fly in agg kernels.
// TUNING LOG (measured):
//  - grid.sync ~30us/barrier on gfx950 — never fuse cheap kernels with it (r5).
//  - agg gather unroll: 4-deep = VGPR 36 / occ 59% / best; 8-deep REGRESSION (r9).
//  - Harness ws-poison fill (~44us, 268MB) is a fixed floor in the trace.
//  - r10: degcount∥prep + lookback scan + cursor-seed GOOD; scatter∥gemm12
//    fusion BAD (scatter blocks inherited 45KB LDS).
//  - r11/r12: unfuse scatter GOOD. Direct-fragment loads REGRESS if they sit
//    after a barrier (serial L2 chain, MfmaUtil 3.2).
//  - r13/r14 WIN: register-hoist W1 fragment loads above the barrier.
//    gemm12 48-54 -> <44. Total 268.6 -> 265.4.
//  - r15 NEUTRAL: packed f32x2 agg accumulators (agg_l1 45 -> <43.2, total
//    flat within noise). Keep — strictly fewer VALU ops.
//  - r16 (this round): gemm_mfma_nt (layer-2 GEMM) is structurally the worst
//    remaining kernel: 196 blocks on 256 CUs (1 wave/SIMD, zero TLP) x 16
//    K-steps x 2 barriers = fully exposed latency. Replace with gemm2_direct:
//    zero-LDS, zero-barrier, both operands load per-lane fragments straight
//    from linear global (A rows 64B segments; B^T 128KB L2-hot), 64-row
//    tiles -> 391 blocks. ILP (no barriers => compiler pipelines ~96 loads)
//    replaces TLP.

#define LRELU(x) ((x) > 0.f ? (x) : 0.2f * (x))

typedef short bf16x8 __attribute__((ext_vector_type(8)));
typedef float f32x4 __attribute__((ext_vector_type(4)));
typedef float f32x2 __attribute__((ext_vector_type(2)));

static __device__ __forceinline__ unsigned short f2b(float f) {
    union { float f; unsigned u; } x; x.f = f;
    unsigned r = x.u + 0x7fff + ((x.u >> 16) & 1);
    return (unsigned short)(r >> 16);
}
static __device__ __forceinline__ float rl_f(float v, int c) {
    return __int_as_float(__builtin_amdgcn_readlane(__float_as_int(v), c));
}
static __device__ __forceinline__ unsigned char f2fp8(float v) {
    int p = __builtin_amdgcn_cvt_pk_fp8_f32(v, v, 0, false);
    return (unsigned char)(p & 0xff);
}

// ---------------- zero scratch (deg + pool + done + scan flags/aggs) ----------
__global__ void zero_kernel(int* __restrict__ deg, float* __restrict__ pool,
                            int* __restrict__ done, int* __restrict__ flg,
                            int* __restrict__ agg, int N, int nb) {
    int i = blockIdx.x * blockDim.x + threadIdx.x;
    if (i < N) { deg[i] = 0; return; }
    i -= N;
    if (i < 128) { pool[i] = 0.f; return; }
    i -= 128;
    if (i == 0) { *done = 0; return; }
    i -= 1;
    if (i < nb) { flg[i] = 0; return; }
    i -= nb;
    if (i < nb) agg[i] = 0;
}

// ---------------- fused: degree count (atomics) ∥ prep conversions ------------
// prep writes MFMA-fragment-swizzled bf16 layouts so the GEMM loads fragments
// directly from global (coalesced 1KiB per wave-fragment):
//   xbS idx(r,k)  = (r>>4)*1024 + (k>>3)*128 + (r&15)*8 + (k&7)      [r<25000,k<64]
//   WeS idx(n,k)  = (n>>4)*1024 + (k>>5)*512 + ((k>>3)&3)*128 + (n&15)*8 + (k&7)
//   W1S idx(n,k)  = (n>>4)*2048 + (k>>5)*512 + ((k>>3)&3)*128 + (n&15)*8 + (k&7)
__global__ void degcount_prep(const int* __restrict__ ei, int E, int N,
                              int* __restrict__ deg, int blocksE,
                              const float* __restrict__ x, const float* __restrict__ We,
                              const float* __restrict__ W1, const float* __restrict__ W2,
                              unsigned short* __restrict__ xbS, unsigned short* __restrict__ WeS,
                              unsigned short* __restrict__ W1S, unsigned short* __restrict__ W2T,
                              int Nx) {
    if ((int)blockIdx.x < blocksE) {
        int i = blockIdx.x * blockDim.x + threadIdx.x;
        if (i < E) atomicAdd(&deg[ei[E + i]], 1);
        else if (i < E + N) atomicAdd(&deg[i - E], 1);
        return;
    }
    int i = (blockIdx.x - blocksE) * blockDim.x + threadIdx.x;
    if (i < Nx) {
        int r = i >> 6, k = i & 63;
        xbS[(r >> 4) * 1024 + (k >> 3) * 128 + (r & 15) * 8 + (k & 7)] = f2b(x[i]);
        return;
    }
    i -= Nx;
    if (i < 64 * 128) {
        int k = i >> 7, n = i & 127;
        WeS[(n >> 4) * 1024 + (k >> 5) * 512 + ((k >> 3) & 3) * 128 + (n & 15) * 8 + (k & 7)] = f2b(We[i]);
        return;
    }
    i -= 64 * 128;
    if (i < 128 * 512) {
        int k = i >> 9, n = i & 511;
        W1S[(n >> 4) * 2048 + (k >> 5) * 512 + ((k >> 3) & 3) * 128 + (n & 15) * 8 + (k & 7)] = f2b(W1[i]);
        return;
    }
    i -= 128 * 512;
    if (i < 512 * 128) { int k = i >> 7, n = i & 127; W2T[n * 512 + k] = f2b(W2[i]); return; }
}

// ---------------- single-dispatch exclusive scan (decoupled lookback) ---------
// nb = 98 blocks <= 256 CUs -> all blocks co-resident, spin cannot deadlock.
// Agent-scope release/acquire handles cross-XCD L2 non-coherence. Seeds
// cursor[i] = rowptr[i] so scatter needs only atomicAdd(&cursor[d],1).
__global__ __launch_bounds__(256) void scan_lookback(const int* __restrict__ deg,
                                                     int* __restrict__ rowptr,
                                                     int* __restrict__ cursor,
                                                     int* __restrict__ agg,
                                                     int* __restrict__ flg,
                                                     int N, int nb) {
    __shared__ int sd[256];
    __shared__ int soff;
    int t = threadIdx.x, b = blockIdx.x;
    int i = b * 256 + t;
    int d = (i < N) ? deg[i] : 0;
    sd[t] = d;
    __syncthreads();
    for (int off = 1; off < 256; off <<= 1) {
        int v = (t >= off) ? sd[t - off] : 0;
        __syncthreads();
        sd[t] += v;
        __syncthreads();
    }
    int incl = sd[t];
    int btot = sd[255];
    if (t == 0) {
        soff = 0;
        __hip_atomic_store(&agg[b], btot, __ATOMIC_RELAXED, __HIP_MEMORY_SCOPE_AGENT);
        __hip_atomic_store(&flg[b], 1, __ATOMIC_RELEASE, __HIP_MEMORY_SCOPE_AGENT);
    }
    if (b > 0 && t < 64) {
        int acc = 0;
        for (int p = t; p < b; p += 64) {
            while (__hip_atomic_load(&flg[p], __ATOMIC_ACQUIRE, __HIP_MEMORY_SCOPE_AGENT) == 0)
                __builtin_amdgcn_s_sleep(1);
            acc += __hip_atomic_load(&agg[p], __ATOMIC_RELAXED, __HIP_MEMORY_SCOPE_AGENT);
        }
#pragma unroll
        for (int o = 32; o >= 1; o >>= 1) acc += __shfl_xor(acc, o);
        if (t == 0) soff = acc;
    }
    __syncthreads();
    int off = soff;
    int excl = off + incl - d;
    if (i < N) { rowptr[i] = excl; cursor[i] = excl; }
    if (b == nb - 1 && t == 255) rowptr[N] = off + btot;
}

// ---------------- CSR scatter (tiny, zero LDS, full occupancy) ----------------
__global__ void scatter_kernel(const int* __restrict__ ei, int E, int N,
                               int* __restrict__ cursor, int* __restrict__ esrc) {
    int i = blockIdx.x * blockDim.x + threadIdx.x;
    int s, d;
    if (i < E) { s = ei[i]; d = ei[E + i]; }
    else if (i < E + N) { s = i - E; d = s; }
    else return;
    int pos = atomicAdd(&cursor[d], 1);
    esrc[pos] = s;
}

// ---------------- fused GEMM1+2: h1 = relu(x@We+be)@W1, fp8 out + alpha -------
// Direct fragment loads from swizzled global layouts. All 16 phase-2 W1
// fragments are loaded into registers BEFORE the h0 epilogue + barrier, so
// their L2 latency hides under the epilogue/barrier/LDS reads. Phase 2 has
// zero global loads. __launch_bounds__(256,3): grid is 3.06 blk/CU, pin
// regalloc to that regime (~170 VGPR budget).
__global__ __launch_bounds__(256, 3) void gemm12_fused(const unsigned short* __restrict__ xbS,
                                                       const unsigned short* __restrict__ WeS,
                                                       const float* __restrict__ b_emb,
                                                       const unsigned short* __restrict__ W1S,
                                                       unsigned char* __restrict__ C8,  // [M,512] fp8
                                                       const float* __restrict__ a_src,
                                                       const float* __restrict__ a_dst,
                                                       float* __restrict__ as_out,
                                                       float* __restrict__ ad_out, int M) {
    __shared__ __align__(16) unsigned short h0s[128 * 132];
    __shared__ float sAl[128][2];

    int tid = threadIdx.x;
    int bx = blockIdx.x, by = blockIdx.y;
    int gm0 = by * 128, gn0 = bx * 128;
    int w = tid >> 6, lane = tid & 63;
    int wrow = (w >> 1) * 64, wc = w & 1, wcol = wc * 64;
    int l15 = lane & 15, quad = lane >> 4;

    f32x4 acc[4][4];
#pragma unroll
    for (int i = 0; i < 4; i++)
#pragma unroll
        for (int j = 0; j < 4; j++) acc[i][j] = {0.f, 0.f, 0.f, 0.f};

    // ---- phase 1: emb GEMM (K=64), direct fragment loads ----
    const unsigned short* xA = xbS + (size_t)((gm0 + wrow) >> 4) * 1024 + quad * 128 + l15 * 8;
    const unsigned short* wB = WeS + (size_t)(wc * 4) * 1024 + quad * 128 + l15 * 8;
    const unsigned short* w1B = W1S + (size_t)(bx * 8 + wc * 4) * 2048 + quad * 128 + l15 * 8;
#pragma unroll
    for (int ks = 0; ks < 2; ks++) {
        bf16x8 af[4], bfr[4];
#pragma unroll
        for (int i = 0; i < 4; i++) af[i] = *(const bf16x8*)(xA + i * 1024 + ks * 512);
#pragma unroll
        for (int j = 0; j < 4; j++) bfr[j] = *(const bf16x8*)(wB + j * 1024 + ks * 512);
#pragma unroll
        for (int i = 0; i < 4; i++)
#pragma unroll
            for (int j = 0; j < 4; j++)
                acc[i][j] = __builtin_amdgcn_mfma_f32_16x16x32_bf16(af[i], bfr[j], acc[i][j], 0, 0, 0);
    }

    // ---- issue ALL phase-2 W1 fragment loads now (latency hides under the
    //      h0 epilogue + barrier + phase-2 LDS reads) ----
    bf16x8 wp[4][4];
#pragma unroll
    for (int ks = 0; ks < 4; ks++)
#pragma unroll
        for (int j = 0; j < 4; j++)
            wp[ks][j] = *(const bf16x8*)(w1B + j * 2048 + ks * 512);

    // ---- h0 = relu(acc + be) -> LDS (bf16), single barrier ----
#pragma unroll
    for (int j = 0; j < 4; j++) {
        int col = wcol + j * 16 + l15;
        float bv = b_emb[col];
#pragma unroll
        for (int i = 0; i < 4; i++) {
            int row = wrow + i * 16 + quad * 4;
#pragma unroll
            for (int r = 0; r < 4; r++) {
                float v = fmaxf(acc[i][j][r] + bv, 0.f);
                h0s[(row + r) * 132 + col] = f2b(v);
            }
        }
    }
#pragma unroll
    for (int i = 0; i < 4; i++)
#pragma unroll
        for (int j = 0; j < 4; j++) acc[i][j] = {0.f, 0.f, 0.f, 0.f};
    __syncthreads();

    // ---- phase 2: h0 @ W1 (K=128), A from LDS, B from registers ----
#pragma unroll
    for (int ks = 0; ks < 4; ks++) {
        bf16x8 af[4];
#pragma unroll
        for (int i = 0; i < 4; i++)
            af[i] = *(const bf16x8*)&h0s[(wrow + i * 16 + l15) * 132 + ks * 32 + quad * 8];
#pragma unroll
        for (int i = 0; i < 4; i++)
#pragma unroll
            for (int j = 0; j < 4; j++)
                acc[i][j] = __builtin_amdgcn_mfma_f32_16x16x32_bf16(af[i], wp[ks][j], acc[i][j], 0, 0, 0);
    }

    // ---- C8 = fp8(h1pre) ----
#pragma unroll
    for (int i = 0; i < 4; i++) {
        int row = gm0 + wrow + i * 16 + quad * 4;
#pragma unroll
        for (int j = 0; j < 4; j++) {
            int col = gn0 + wcol + j * 16 + l15;
#pragma unroll
            for (int r = 0; r < 4; r++) {
                int gr = row + r;
                if (gr < M) C8[(size_t)gr * 512 + col] = f2fp8(acc[i][j][r]);
            }
        }
    }

    // ---- fused alpha dots (f32-exact) ----
    {
        int hh = bx;
        float as_c[4], ad_c[4];
#pragma unroll
        for (int j = 0; j < 4; j++) {
            int c = gn0 + wcol + j * 16 + l15;
            as_c[j] = a_src[c];
            ad_c[j] = a_dst[c];
        }
#pragma unroll
        for (int i = 0; i < 4; i++) {
#pragma unroll
            for (int r = 0; r < 4; r++) {
                float ps = 0.f, pd = 0.f;
#pragma unroll
                for (int j = 0; j < 4; j++) {
                    ps += acc[i][j][r] * as_c[j];
                    pd += acc[i][j][r] * ad_c[j];
                }
#pragma unroll
                for (int o = 1; o < 16; o <<= 1) {
                    ps += __shfl_xor(ps, o);
                    pd += __shfl_xor(pd, o);
                }
                if (wcol == 64 && l15 == 0) {
                    int lr = wrow + i * 16 + quad * 4 + r;
                    sAl[lr][0] = ps;
                    sAl[lr][1] = pd;
                }
            }
        }
        __syncthreads();
        if (wcol == 0) {
#pragma unroll
            for (int i = 0; i < 4; i++) {
#pragma unroll
                for (int r = 0; r < 4; r++) {
                    float ps = 0.f, pd = 0.f;
#pragma unroll
                    for (int j = 0; j < 4; j++) {
                        ps += acc[i][j][r] * as_c[j];
                        pd += acc[i][j][r] * ad_c[j];
                    }
#pragma unroll
                    for (int o = 1; o < 16; o <<= 1) {
                        ps += __shfl_xor(ps, o);
                        pd += __shfl_xor(pd, o);
                    }
                    if (l15 == 0) {
                        int lr = wrow + i * 16 + quad * 4 + r;
                        int gr = gm0 + lr;
                        if (gr < M) {
                            as_out[(size_t)gr * 4 + hh] = ps + sAl[lr][0];
                            ad_out[(size_t)gr * 4 + hh] = pd + sAl[lr][1];
                        }
                    }
                }
            }
        }
    }
}

// ---------------- layer-2 GEMM: zero-LDS direct-fragment, no barriers --------
// h2pre = o1b[25000,512] @ W2 -> [25000,128] fp8 + fused alpha2 (H=1).
// Both operands load per-lane fragments straight from linear global:
//   A row-major: lane reads 16B at row(wrow+i*16+l15), k=k0+quad*8 (64B/row
//   segments); B^T [n][k] is 128KB, L2-hot for every block. No LDS staging,
//   no k-loop barriers -> compiler pipelines loads across the whole K-loop.
// 64-row tiles -> 391 blocks (~1.5/CU) for TLP on top of the ILP.
__global__ __launch_bounds__(256) void gemm2_direct(const unsigned short* __restrict__ A,   // [M,512]
                                                    const unsigned short* __restrict__ Bt,  // [128,512]
                                                    unsigned char* __restrict__ C8,         // [M,128] fp8
                                                    const float* __restrict__ a_src,
                                                    const float* __restrict__ a_dst,
                                                    float* __restrict__ as_out,
                                                    float* __restrict__ ad_out, int M) {
    __shared__ float sAl[64][2];
    int tid = threadIdx.x;
    int gm0 = blockIdx.x * 64;
    int w = tid >> 6, lane = tid & 63;
    int wrow = (w >> 1) * 32, wc = w & 1, wcol = wc * 64;
    int l15 = lane & 15, quad = lane >> 4;

    f32x4 acc[2][4];
#pragma unroll
    for (int i = 0; i < 2; i++)
#pragma unroll
        for (int j = 0; j < 4; j++) acc[i][j] = {0.f, 0.f, 0.f, 0.f};

    int r0 = gm0 + wrow + l15;      if (r0 >= M) r0 = M - 1;   // tail clamp; outputs guarded
    int r1 = gm0 + wrow + 16 + l15; if (r1 >= M) r1 = M - 1;
    const unsigned short* a0 = A + (size_t)r0 * 512 + quad * 8;
    const unsigned short* a1 = A + (size_t)r1 * 512 + quad * 8;
    const unsigned short* b0 = Bt + (size_t)(wcol + l15) * 512 + quad * 8;

#pragma unroll 4
    for (int ks = 0; ks < 16; ks++) {
        bf16x8 af0 = *(const bf16x8*)(a0 + ks * 32);
        bf16x8 af1 = *(const bf16x8*)(a1 + ks * 32);
        bf16x8 bf0 = *(const bf16x8*)(b0 + ks * 32);
        bf16x8 bf1 = *(const bf16x8*)(b0 + 16 * 512 + ks * 32);
        bf16x8 bf2 = *(const bf16x8*)(b0 + 32 * 512 + ks * 32);
        bf16x8 bf3 = *(const bf16x8*)(b0 + 48 * 512 + ks * 32);
        acc[0][0] = __builtin_amdgcn_mfma_f32_16x16x32_bf16(af0, bf0, acc[0][0], 0, 0, 0);
        acc[0][1] = __builtin_amdgcn_mfma_f32_16x16x32_bf16(af0, bf1, acc[0][1], 0, 0, 0);
        acc[0][2] = __builtin_amdgcn_mfma_f32_16x16x32_bf16(af0, bf2, acc[0][2], 0, 0, 0);
        acc[0][3] = __builtin_amdgcn_mfma_f32_16x16x32_bf16(af0, bf3, acc[0][3], 0, 0, 0);
        acc[1][0] = __builtin_amdgcn_mfma_f32_16x16x32_bf16(af1, bf0, acc[1][0], 0, 0, 0);
        acc[1][1] = __builtin_amdgcn_mfma_f32_16x16x32_bf16(af1, bf1, acc[1][1], 0, 0, 0);
        acc[1][2] = __builtin_amdgcn_mfma_f32_16x16x32_bf16(af1, bf2, acc[1][2], 0, 0, 0);
        acc[1][3] = __builtin_amdgcn_mfma_f32_16x16x32_bf16(af1, bf3, acc[1][3], 0, 0, 0);
    }

    // ---- C8 = fp8(h2pre) ----
#pragma unroll
    for (int i = 0; i < 2; i++) {
        int row = gm0 + wrow + i * 16 + quad * 4;
#pragma unroll
        for (int j = 0; j < 4; j++) {
            int col = wcol + j * 16 + l15;
#pragma unroll
            for (int r = 0; r < 4; r++) {
                int gr = row + r;
                if (gr < M) C8[(size_t)gr * 128 + col] = f2fp8(acc[i][j][r]);
            }
        }
    }

    // ---- fused alpha dots (H=1, f32-exact) ----
    {
        float as_c[4], ad_c[4];
#pragma unroll
        for (int j = 0; j < 4; j++) {
            int c = wcol + j * 16 + l15;
            as_c[j] = a_src[c];
            ad_c[j] = a_dst[c];
        }
#pragma unroll
        for (int i = 0; i < 2; i++) {
#pragma unroll
            for (int r = 0; r < 4; r++) {
                float ps = 0.f, pd = 0.f;
#pragma unroll
                for (int j = 0; j < 4; j++) {
                    ps += acc[i][j][r] * as_c[j];
                    pd += acc[i][j][r] * ad_c[j];
                }
#pragma unroll
                for (int o = 1; o < 16; o <<= 1) {
                    ps += __shfl_xor(ps, o);
                    pd += __shfl_xor(pd, o);
                }
                if (wcol == 64 && l15 == 0) {
                    int lr = wrow + i * 16 + quad * 4 + r;
                    sAl[lr][0] = ps;
                    sAl[lr][1] = pd;
                }
            }
        }
        __syncthreads();
        if (wcol == 0) {
#pragma unroll
            for (int i = 0; i < 2; i++) {
#pragma unroll
                for (int r = 0; r < 4; r++) {
                    float ps = 0.f, pd = 0.f;
#pragma unroll
                    for (int j = 0; j < 4; j++) {
                        ps += acc[i][j][r] * as_c[j];
                        pd += acc[i][j][r] * ad_c[j];
                    }
#pragma unroll
                    for (int o = 1; o < 16; o <<= 1) {
                        ps += __shfl_xor(ps, o);
                        pd += __shfl_xor(pd, o);
                    }
                    if (l15 == 0) {
                        int lr = wrow + i * 16 + quad * 4 + r;
                        int gr = gm0 + lr;
                        if (gr < M) {
                            as_out[gr] = ps + sAl[lr][0];
                            ad_out[gr] = pd + sAl[lr][1];
                        }
                    }
                }
            }
        }
    }
}

// ---------------- GAT agg L1 (H=4): 1 wave/node, fp8 gather, 4-edge MLP -------
// 4-edge unroll is the measured sweet spot (VGPR 36 / occ 59%); 8-deep regressed.
// r15: packed f32x2 accumulators — cvt_pk_f32_fp8 pairs feed v_pk_fma_f32.
__global__ __launch_bounds__(256) void gat_agg_l1(const unsigned* __restrict__ hq,
                                                  const float4* __restrict__ as4,
                                                  const float4* __restrict__ ad4,
                                                  const int* __restrict__ rowptr,
                                                  const int* __restrict__ esrc,
                                                  const float* __restrict__ bias,
                                                  unsigned short* __restrict__ out, int N) {
    __shared__ float wlds_all[4][256];
    int w = threadIdx.x >> 6, lane = threadIdx.x & 63;
    int n = blockIdx.x * 4 + w;
    if (n >= N) return;
    float* wlds = wlds_all[w];
    int2 rp = *(const int2*)&rowptr[n];    // one 8B load: begin, end
    int begin = rp.x, deg = rp.y - rp.x;
    float4 adn = ad4[n];

    int s_l0 = 0;
    float4 e0 = {-3.4e38f, -3.4e38f, -3.4e38f, -3.4e38f};
    if (lane < deg) {
        s_l0 = esrc[begin + lane];
        float4 u = as4[s_l0];
        e0.x = LRELU(u.x + adn.x); e0.y = LRELU(u.y + adn.y);
        e0.z = LRELU(u.z + adn.z); e0.w = LRELU(u.w + adn.w);
    }
    float4 m = e0;
    for (int base = 64; base < deg; base += 64) {
        int j = base + lane;
        if (j < deg) {
            float4 u = as4[esrc[begin + j]];
            m.x = fmaxf(m.x, LRELU(u.x + adn.x)); m.y = fmaxf(m.y, LRELU(u.y + adn.y));
            m.z = fmaxf(m.z, LRELU(u.z + adn.z)); m.w = fmaxf(m.w, LRELU(u.w + adn.w));
        }
    }
#pragma unroll
    for (int o = 32; o >= 1; o >>= 1) {
        m.x = fmaxf(m.x, __shfl_xor(m.x, o));
        m.y = fmaxf(m.y, __shfl_xor(m.y, o));
        m.z = fmaxf(m.z, __shfl_xor(m.z, o));
        m.w = fmaxf(m.w, __shfl_xor(m.w, o));
    }
    float4 s4 = {0.f, 0.f, 0.f, 0.f};
    if (lane < deg) {
        s4.x = __expf(e0.x - m.x); s4.y = __expf(e0.y - m.y);
        s4.z = __expf(e0.z - m.z); s4.w = __expf(e0.w - m.w);
    }
    for (int base = 64; base < deg; base += 64) {
        int j = base + lane;
        if (j < deg) {
            float4 u = as4[esrc[begin + j]];
            s4.x += __expf(LRELU(u.x + adn.x) - m.x); s4.y += __expf(LRELU(u.y + adn.y) - m.y);
            s4.z += __expf(LRELU(u.z + adn.z) - m.z); s4.w += __expf(LRELU(u.w + adn.w) - m.w);
        }
    }
#pragma unroll
    for (int o = 32; o >= 1; o >>= 1) {
        s4.x += __shfl_xor(s4.x, o); s4.y += __shfl_xor(s4.y, o);
        s4.z += __shfl_xor(s4.z, o); s4.w += __shfl_xor(s4.w, o);
    }
    float4 inv = {1.f / (s4.x + 1e-16f), 1.f / (s4.y + 1e-16f),
                  1.f / (s4.z + 1e-16f), 1.f / (s4.w + 1e-16f)};

    f32x2 acc2[4] = {};
    int h = lane >> 4;
#define ACC_E1(q, wgt) { \
    f32x2 wv = {wgt, wgt}; \
    acc2[0] += wv * __builtin_amdgcn_cvt_pk_f32_fp8((int)q.x, false); \
    acc2[1] += wv * __builtin_amdgcn_cvt_pk_f32_fp8((int)q.x, true);  \
    acc2[2] += wv * __builtin_amdgcn_cvt_pk_f32_fp8((int)q.y, false); \
    acc2[3] += wv * __builtin_amdgcn_cvt_pk_f32_fp8((int)q.y, true);  }

    for (int base = 0; base < deg; base += 64) {
        int j = base + lane;
        int len = min(64, deg - base);
        int s_l = s_l0;
        float4 e = e0;
        if (base > 0 && j < deg) {
            s_l = esrc[begin + j];
            float4 u = as4[s_l];
            e.x = LRELU(u.x + adn.x); e.y = LRELU(u.y + adn.y);
            e.z = LRELU(u.z + adn.z); e.w = LRELU(u.w + adn.w);
        }
        if (j < deg) {
            float4 wv4 = {__expf(e.x - m.x) * inv.x, __expf(e.y - m.y) * inv.y,
                          __expf(e.z - m.z) * inv.z, __expf(e.w - m.w) * inv.w};
            *(float4*)&wlds[lane * 4] = wv4;
        }
        int c = 0;
        for (; c + 4 <= len; c += 4) {
            int s0 = __builtin_amdgcn_readlane(s_l, c);
            int s1 = __builtin_amdgcn_readlane(s_l, c + 1);
            int s2 = __builtin_amdgcn_readlane(s_l, c + 2);
            int s3 = __builtin_amdgcn_readlane(s_l, c + 3);
            uint2 q0 = *((const uint2*)(hq + (size_t)s0 * 128) + lane);
            uint2 q1 = *((const uint2*)(hq + (size_t)s1 * 128) + lane);
            uint2 q2 = *((const uint2*)(hq + (size_t)s2 * 128) + lane);
            uint2 q3 = *((const uint2*)(hq + (size_t)s3 * 128) + lane);
            float w0 = wlds[c * 4 + h];
            float w1 = wlds[c * 4 + 4 + h];
            float w2 = wlds[c * 4 + 8 + h];
            float w3 = wlds[c * 4 + 12 + h];
            ACC_E1(q0, w0); ACC_E1(q1, w1); ACC_E1(q2, w2); ACC_E1(q3, w3);
        }
        for (; c < len; c++) {
            int s0 = __builtin_amdgcn_readlane(s_l, c);
            uint2 q0 = *((const uint2*)(hq + (size_t)s0 * 128) + lane);
            float w0 = wlds[c * 4 + h];
            ACC_E1(q0, w0);
        }
    }
#undef ACC_E1
    int f0 = lane * 8;
    unsigned pk[4];
#pragma unroll
    for (int k = 0; k < 4; k++) {
        float v0 = acc2[k].x + bias[f0 + 2 * k];
        float v1 = acc2[k].y + bias[f0 + 2 * k + 1];
        v0 = v0 > 0.f ? v0 : (__expf(v0) - 1.f);
        v1 = v1 > 0.f ? v1 : (__expf(v1) - 1.f);
        pk[k] = (unsigned)f2b(v0) | ((unsigned)f2b(v1) << 16);
    }
    uint4 pv = {pk[0], pk[1], pk[2], pk[3]};
    *((uint4*)(out + (size_t)n * 512) + lane) = pv;
}

// ---------------- GAT agg L2 (H=1): 1 wave/node, fp8 gather, 4-edge MLP -------
// r15: packed f32x2 accumulator.
__global__ __launch_bounds__(256) void gat_agg_l2(const unsigned char* __restrict__ hq,
                                                  const float* __restrict__ as,
                                                  const float* __restrict__ ad,
                                                  const int* __restrict__ rowptr,
                                                  const int* __restrict__ esrc,
                                                  const float* __restrict__ bias,
                                                  float* __restrict__ out, int N) {
    int w = threadIdx.x >> 6, lane = threadIdx.x & 63;
    int n = blockIdx.x * 4 + w;
    if (n >= N) return;
    int2 rp = *(const int2*)&rowptr[n];
    int begin = rp.x, deg = rp.y - rp.x;
    float adn = ad[n];

    int s_l0 = 0;
    float e0 = -3.4e38f;
    if (lane < deg) {
        s_l0 = esrc[begin + lane];
        e0 = LRELU(as[s_l0] + adn);
    }
    float m = e0;
    for (int base = 64; base < deg; base += 64) {
        int j = base + lane;
        if (j < deg) m = fmaxf(m, LRELU(as[esrc[begin + j]] + adn));
    }
#pragma unroll
    for (int o = 32; o >= 1; o >>= 1) m = fmaxf(m, __shfl_xor(m, o));

    float s = (lane < deg) ? __expf(e0 - m) : 0.f;
    for (int base = 64; base < deg; base += 64) {
        int j = base + lane;
        if (j < deg) s += __expf(LRELU(as[esrc[begin + j]] + adn) - m);
    }
#pragma unroll
    for (int o = 32; o >= 1; o >>= 1) s += __shfl_xor(s, o);
    float inv = 1.f / (s + 1e-16f);

    f32x2 acc2 = {0.f, 0.f};
    for (int base = 0; base < deg; base += 64) {
        int j = base + lane;
        int len = min(64, deg - base);
        int s_l = s_l0;
        float e = e0;
        if (base > 0 && j < deg) {
            s_l = esrc[begin + j];
            e = LRELU(as[s_l] + adn);
        }
        float w_l = (j < deg) ? __expf(e - m) * inv : 0.f;
        int c = 0;
        for (; c + 4 <= len; c += 4) {
            int sp0 = __builtin_amdgcn_readlane(s_l, c);
            int sp1 = __builtin_amdgcn_readlane(s_l, c + 1);
            int sp2 = __builtin_amdgcn_readlane(s_l, c + 2);
            int sp3 = __builtin_amdgcn_readlane(s_l, c + 3);
            unsigned short u0 = *((const unsigned short*)(hq + (size_t)sp0 * 128) + lane);
            unsigned short u1 = *((const unsigned short*)(hq + (size_t)sp1 * 128) + lane);
            unsigned short u2 = *((const unsigned short*)(hq + (size_t)sp2 * 128) + lane);
            unsigned short u3 = *((const unsigned short*)(hq + (size_t)sp3 * 128) + lane);
            float w0 = rl_f(w_l, c), w1 = rl_f(w_l, c + 1);
            float w2 = rl_f(w_l, c + 2), w3 = rl_f(w_l, c + 3);
            f32x2 wv0 = {w0, w0}, wv1 = {w1, w1}, wv2 = {w2, w2}, wv3 = {w3, w3};
            acc2 += wv0 * __builtin_amdgcn_cvt_pk_f32_fp8((int)u0, false);
            acc2 += wv1 * __builtin_amdgcn_cvt_pk_f32_fp8((int)u1, false);
            acc2 += wv2 * __builtin_amdgcn_cvt_pk_f32_fp8((int)u2, false);
            acc2 += wv3 * __builtin_amdgcn_cvt_pk_f32_fp8((int)u3, false);
        }
        for (; c < len; c++) {
            int sp0 = __builtin_amdgcn_readlane(s_l, c);
            float w0 = rl_f(w_l, c);
            unsigned short u0 = *((const unsigned short*)(hq + (size_t)sp0 * 128) + lane);
            f32x2 wv0 = {w0, w0};
            acc2 += wv0 * __builtin_amdgcn_cvt_pk_f32_fp8((int)u0, false);
        }
    }
    float v0 = acc2.x + bias[lane * 2];
    float v1 = acc2.y + bias[lane * 2 + 1];
    v0 = v0 > 0.f ? v0 : (__expf(v0) - 1.f);
    v1 = v1 > 0.f ? v1 : (__expf(v1) - 1.f);
    float2 pv = {v0, v1};
    *(float2*)&out[(size_t)n * 128 + lane * 2] = pv;
}

// ---------------- mean pool + final GEMV (fused via done-counter) -------------
__global__ __launch_bounds__(256) void pool_final_kernel(const float* __restrict__ o2,
                                                         float* __restrict__ pool,
                                                         int* __restrict__ done,
                                                         const float* __restrict__ Wout,
                                                         const float* __restrict__ bout,
                                                         float* __restrict__ out,
                                                         int N, int nblocks, float invN) {
    __shared__ float4 sred[256];
    int f4 = threadIdx.x & 31;
    int r = blockIdx.x * 256 + (threadIdx.x >> 5);
    float4 acc = {0.f, 0.f, 0.f, 0.f};
    for (int i = 0; i < 32; i++, r += 8) {
        if (r < N) {
            float4 v = *(const float4*)&o2[(size_t)r * 128 + f4 * 4];
            acc.x += v.x; acc.y += v.y; acc.z += v.z; acc.w += v.w;
        }
    }
    sred[threadIdx.x] = acc;
    __syncthreads();
    if (threadIdx.x < 32) {
        float4 t = sred[threadIdx.x];
#pragma unroll
        for (int k = 1; k < 8; k++) {
            float4 u = sred[threadIdx.x + 32 * k];
            t.x += u.x; t.y += u.y; t.z += u.z; t.w += u.w;
        }
        atomicAdd(&pool[f4 * 4 + 0], t.x);
        atomicAdd(&pool[f4 * 4 + 1], t.y);
        atomicAdd(&pool[f4 * 4 + 2], t.z);
        atomicAdd(&pool[f4 * 4 + 3], t.w);
    }
    __threadfence();
    __shared__ int isLast;
    if (threadIdx.x == 0) isLast = (atomicAdd(done, 1) == nblocks - 1);
    __syncthreads();
    if (isLast) {
        __shared__ float spool[128];
        if (threadIdx.x < 128) spool[threadIdx.x] = atomicAdd(&pool[threadIdx.x], 0.f);
        __syncthreads();
        int o = threadIdx.x;
        float a = 0.f;
        for (int k = 0; k < 128; k++) a += spool[k] * Wout[k * 256 + o];
        out[o] = a * invN + bout[o];
    }
}

// ---------------- launch ------------------------------------------------------
extern "C" void kernel_launch(void* const* d_in, const int* in_sizes, int n_in,
                              void* d_out, int out_size, void* d_ws, size_t ws_size,
                              hipStream_t stream) {
    const float* x      = (const float*)d_in[0];
    const int*   ei     = (const int*)d_in[1];
    const float* W_emb  = (const float*)d_in[2];
    const float* b_emb  = (const float*)d_in[3];
    const float* W1     = (const float*)d_in[4];
    const float* a1_src = (const float*)d_in[5];
    const float* a1_dst = (const float*)d_in[6];
    const float* b1     = (const float*)d_in[7];
    const float* W2     = (const float*)d_in[8];
    const float* a2_src = (const float*)d_in[9];
    const float* a2_dst = (const float*)d_in[10];
    const float* b2     = (const float*)d_in[11];
    const float* W_out  = (const float*)d_in[12];
    const float* b_out  = (const float*)d_in[13];
    float* out = (float*)d_out;

    const int N = in_sizes[0] / 64;   // 25000
    const int E = in_sizes[1] / 2;    // 400000
    const int Etot = E + N;
    const int nb = (N + 255) / 256;   // 98 blocks — must stay <= CU count (lookback co-residency)
    const int mtiles = (N + 127) / 128;   // 196
    const int nrb = mtiles * 8;           // 16-row fragment blocks incl. tail

    char* ws = (char*)d_ws;
    size_t off = 0;
    auto alloc = [&](size_t bytes) -> void* {
        void* p = ws + off;
        off = (off + bytes + 255) & ~(size_t)255;
        return p;
    };
    typedef unsigned short u16;
    u16* xbS   = (u16*)alloc((size_t)nrb * 1024 * 2);     // frag-swizzled x (bf16)
    u16* WeS   = (u16*)alloc((size_t)8 * 1024 * 2);       // frag-swizzled We
    u16* W1S   = (u16*)alloc((size_t)32 * 2048 * 2);      // frag-swizzled W1
    u16* W2T   = (u16*)alloc((size_t)128 * 512 * 2);
    unsigned char* h1q = (unsigned char*)alloc((size_t)N * 512);   // fp8
    u16* o1b   = (u16*)alloc((size_t)N * 512 * 2);
    unsigned char* h2q = (unsigned char*)alloc((size_t)N * 128);   // fp8
    float* o2  = (float*)alloc((size_t)N * 128 * 4);
    float* as1 = (float*)alloc((size_t)N * 4 * 4);
    float* ad1 = (float*)alloc((size_t)N * 4 * 4);
    float* as2 = (float*)alloc((size_t)N * 4);
    float* ad2 = (float*)alloc((size_t)N * 4);
    float* pool = (float*)alloc(128 * 4);
    int* done   = (int*)alloc(256);
    int* rowptr = (int*)alloc((size_t)(N + 1) * 4);
    int* deg    = (int*)alloc((size_t)N * 4);
    int* cursor = (int*)alloc((size_t)N * 4);
    int* sagg   = (int*)alloc((size_t)nb * 4);
    int* sflg   = (int*)alloc((size_t)nb * 4);
    int* esrc   = (int*)alloc((size_t)Etot * 4);

    const int blocksE = (Etot + 255) / 256;
    const int Nx = N * 64;
    const int prepElems = Nx + 64 * 128 + 128 * 512 + 512 * 128;
    const int prepBlocks = (prepElems + 255) / 256;

    // K1: zero deg/pool/done + scan flags & aggs
    int zn = N + 128 + 1 + 2 * nb;
    zero_kernel<<<(zn + 255) / 256, 256, 0, stream>>>(deg, pool, done, sflg, sagg, N, nb);

    // K2: degree histogram (atomics) ∥ swizzled bf16 conversions
    degcount_prep<<<blocksE + prepBlocks, 256, 0, stream>>>(ei, E, N, deg, blocksE,
                                                            x, W_emb, W1, W2,
                                                            xbS, WeS, W1S, W2T, Nx);

    // K3: single-dispatch exclusive scan (decoupled lookback) + cursor seed
    scan_lookback<<<nb, 256, 0, stream>>>(deg, rowptr, cursor, sagg, sflg, N, nb);

    // K4: CSR scatter (tiny, full occupancy)
    scatter_kernel<<<blocksE, 256, 0, stream>>>(ei, E, N, cursor, esrc);

    // K5: fused GEMM1+2 (h1pre = relu(x@We+be)@W1, fp8 + alpha1)
    gemm12_fused<<<dim3(4, mtiles), 256, 0, stream>>>(xbS, WeS, b_emb, W1S, h1q,
                                                      a1_src, a1_dst, as1, ad1, N);

    // K6: layer-1 aggregation (logits on the fly, fp8 gather)
    gat_agg_l1<<<(N + 3) / 4, 256, 0, stream>>>((const unsigned*)h1q, (const float4*)as1,
                                                (const float4*)ad1, rowptr, esrc, b1, o1b, N);

    // K7: h2pre = o1 @ W2  [N,128] fp8 + fused alpha2 (zero-LDS direct)
    gemm2_direct<<<dim3((N + 63) / 64), 256, 0, stream>>>(
        o1b, W2T, h2q, a2_src, a2_dst, as2, ad2, N);

    // K8: layer-2 aggregation
    gat_agg_l2<<<(N + 3) / 4, 256, 0, stream>>>(h2q, as2, ad2, rowptr, esrc, b2, o2, N);

    // K9: mean pool + final GEMV
    int npb = (N + 255) / 256;
    pool_final_kernel<<<npb, 256, 0, stream>>>(o2, pool, done, W_out, b_out, out,
                                               N, npb, 1.f / (float)N);
}

// Round 9
// 270.554 us; speedup vs baseline: 1.0139x; 1.0139x over previous
//
#include <hip/hip_runtime.h>
#include <hip/hip_bf16.h>

// N=25000, E=400000 (+N self loops), F_IN=64, HID=128, HEADS=4, OUT=256
// bf16 MFMA GEMMs (embed GEMM fused into layer-1 GEMM via LDS round-trip);
// node-feature gather operands stored fp8(e4m3); alpha dots fused into GEMM
// epilogues (f32-exact); edge logits computed on the fly in agg kernels.
// TUNING LOG (measured):
//  - grid.sync ~30us/barrier on gfx950 — never fuse cheap kernels with it (r5).
//  - agg gather unroll: 4-deep = VGPR 36 / occ 59% / best; 8-deep REGRESSION (r9).
//  - Harness ws-poison fill (~44us, 268MB) is a fixed floor in the trace.
//  - r10: degcount∥prep + lookback scan + cursor-seed GOOD; scatter∥gemm12
//    fusion BAD (scatter blocks inherited 45KB LDS).
//  - r11/r12: unfuse scatter GOOD. Direct-fragment loads REGRESS if they sit
//    after a barrier (serial L2 chain).
//  - r13/r14 WIN: register-hoist W1 fragment loads above the barrier.
//    gemm12 48-54 -> <44. Total 268.6 -> 265.4 (best).
//  - r15 NEUTRAL: packed f32x2 agg accumulators (agg_l1 45 -> <43.2). Keep.
//  - r16 REGRESSION (+5us): replaced never-measured gemm_mfma_nt with
//    gemm2_direct on structural theory alone. Lesson: don't rewrite
//    unmeasured kernels. REVERTED in r17.
//  - r17: (a) revert to gemm_mfma_nt for layer-2. (b) gemm12: 2-way column
//    split (grid 2x196=392). Phase-1 emb GEMM redundancy 4x->2x, xbS fetch
//    12.8->6.4MB. Half-0 W1 frags hoisted pre-barrier (r13 rule); half-1
//    frags issued after half-0 MFMAs, hidden under half-0's epilogue.
//  - r18 (this round): identical resubmit of r17 — GPUAcquisitionTimeout
//    (broker capacity). Kernel never executed; no data, no changes.

#define LRELU(x) ((x) > 0.f ? (x) : 0.2f * (x))

typedef short bf16x8 __attribute__((ext_vector_type(8)));
typedef float f32x4 __attribute__((ext_vector_type(4)));
typedef float f32x2 __attribute__((ext_vector_type(2)));

static __device__ __forceinline__ unsigned short f2b(float f) {
    union { float f; unsigned u; } x; x.f = f;
    unsigned r = x.u + 0x7fff + ((x.u >> 16) & 1);
    return (unsigned short)(r >> 16);
}
static __device__ __forceinline__ float rl_f(float v, int c) {
    return __int_as_float(__builtin_amdgcn_readlane(__float_as_int(v), c));
}
static __device__ __forceinline__ unsigned char f2fp8(float v) {
    int p = __builtin_amdgcn_cvt_pk_fp8_f32(v, v, 0, false);
    return (unsigned char)(p & 0xff);
}

// ---------------- zero scratch (deg + pool + done + scan flags/aggs) ----------
__global__ void zero_kernel(int* __restrict__ deg, float* __restrict__ pool,
                            int* __restrict__ done, int* __restrict__ flg,
                            int* __restrict__ agg, int N, int nb) {
    int i = blockIdx.x * blockDim.x + threadIdx.x;
    if (i < N) { deg[i] = 0; return; }
    i -= N;
    if (i < 128) { pool[i] = 0.f; return; }
    i -= 128;
    if (i == 0) { *done = 0; return; }
    i -= 1;
    if (i < nb) { flg[i] = 0; return; }
    i -= nb;
    if (i < nb) agg[i] = 0;
}

// ---------------- fused: degree count (atomics) ∥ prep conversions ------------
// prep writes MFMA-fragment-swizzled bf16 layouts so the GEMM loads fragments
// directly from global (coalesced 1KiB per wave-fragment):
//   xbS idx(r,k)  = (r>>4)*1024 + (k>>3)*128 + (r&15)*8 + (k&7)      [r<25000,k<64]
//   WeS idx(n,k)  = (n>>4)*1024 + (k>>5)*512 + ((k>>3)&3)*128 + (n&15)*8 + (k&7)
//   W1S idx(n,k)  = (n>>4)*2048 + (k>>5)*512 + ((k>>3)&3)*128 + (n&15)*8 + (k&7)
__global__ void degcount_prep(const int* __restrict__ ei, int E, int N,
                              int* __restrict__ deg, int blocksE,
                              const float* __restrict__ x, const float* __restrict__ We,
                              const float* __restrict__ W1, const float* __restrict__ W2,
                              unsigned short* __restrict__ xbS, unsigned short* __restrict__ WeS,
                              unsigned short* __restrict__ W1S, unsigned short* __restrict__ W2T,
                              int Nx) {
    if ((int)blockIdx.x < blocksE) {
        int i = blockIdx.x * blockDim.x + threadIdx.x;
        if (i < E) atomicAdd(&deg[ei[E + i]], 1);
        else if (i < E + N) atomicAdd(&deg[i - E], 1);
        return;
    }
    int i = (blockIdx.x - blocksE) * blockDim.x + threadIdx.x;
    if (i < Nx) {
        int r = i >> 6, k = i & 63;
        xbS[(r >> 4) * 1024 + (k >> 3) * 128 + (r & 15) * 8 + (k & 7)] = f2b(x[i]);
        return;
    }
    i -= Nx;
    if (i < 64 * 128) {
        int k = i >> 7, n = i & 127;
        WeS[(n >> 4) * 1024 + (k >> 5) * 512 + ((k >> 3) & 3) * 128 + (n & 15) * 8 + (k & 7)] = f2b(We[i]);
        return;
    }
    i -= 64 * 128;
    if (i < 128 * 512) {
        int k = i >> 9, n = i & 511;
        W1S[(n >> 4) * 2048 + (k >> 5) * 512 + ((k >> 3) & 3) * 128 + (n & 15) * 8 + (k & 7)] = f2b(W1[i]);
        return;
    }
    i -= 128 * 512;
    if (i < 512 * 128) { int k = i >> 7, n = i & 127; W2T[n * 512 + k] = f2b(W2[i]); return; }
}

// ---------------- single-dispatch exclusive scan (decoupled lookback) ---------
// nb = 98 blocks <= 256 CUs -> all blocks co-resident, spin cannot deadlock.
// Agent-scope release/acquire handles cross-XCD L2 non-coherence. Seeds
// cursor[i] = rowptr[i] so scatter needs only atomicAdd(&cursor[d],1).
__global__ __launch_bounds__(256) void scan_lookback(const int* __restrict__ deg,
                                                     int* __restrict__ rowptr,
                                                     int* __restrict__ cursor,
                                                     int* __restrict__ agg,
                                                     int* __restrict__ flg,
                                                     int N, int nb) {
    __shared__ int sd[256];
    __shared__ int soff;
    int t = threadIdx.x, b = blockIdx.x;
    int i = b * 256 + t;
    int d = (i < N) ? deg[i] : 0;
    sd[t] = d;
    __syncthreads();
    for (int off = 1; off < 256; off <<= 1) {
        int v = (t >= off) ? sd[t - off] : 0;
        __syncthreads();
        sd[t] += v;
        __syncthreads();
    }
    int incl = sd[t];
    int btot = sd[255];
    if (t == 0) {
        soff = 0;
        __hip_atomic_store(&agg[b], btot, __ATOMIC_RELAXED, __HIP_MEMORY_SCOPE_AGENT);
        __hip_atomic_store(&flg[b], 1, __ATOMIC_RELEASE, __HIP_MEMORY_SCOPE_AGENT);
    }
    if (b > 0 && t < 64) {
        int acc = 0;
        for (int p = t; p < b; p += 64) {
            while (__hip_atomic_load(&flg[p], __ATOMIC_ACQUIRE, __HIP_MEMORY_SCOPE_AGENT) == 0)
                __builtin_amdgcn_s_sleep(1);
            acc += __hip_atomic_load(&agg[p], __ATOMIC_RELAXED, __HIP_MEMORY_SCOPE_AGENT);
        }
#pragma unroll
        for (int o = 32; o >= 1; o >>= 1) acc += __shfl_xor(acc, o);
        if (t == 0) soff = acc;
    }
    __syncthreads();
    int off = soff;
    int excl = off + incl - d;
    if (i < N) { rowptr[i] = excl; cursor[i] = excl; }
    if (b == nb - 1 && t == 255) rowptr[N] = off + btot;
}

// ---------------- CSR scatter (tiny, zero LDS, full occupancy) ----------------
__global__ void scatter_kernel(const int* __restrict__ ei, int E, int N,
                               int* __restrict__ cursor, int* __restrict__ esrc) {
    int i = blockIdx.x * blockDim.x + threadIdx.x;
    int s, d;
    if (i < E) { s = ei[i]; d = ei[E + i]; }
    else if (i < E + N) { s = i - E; d = s; }
    else return;
    int pos = atomicAdd(&cursor[d], 1);
    esrc[pos] = s;
}

// ---------------- fused GEMM1+2: h1 = relu(x@We+be)@W1, fp8 out + alpha -------
// r17: 2-way column split. Block (bx,by) computes rows by*128..+127, columns
// bx*256..+255 as two 128-col halves. Phase-1 emb GEMM computed once per
// block (2x total redundancy instead of 4x). Half-0 W1 frags hoisted
// pre-barrier (r13 rule); half-1 frags issued after half-0 MFMAs so their
// latency hides under half-0's C8+alpha epilogue.
__global__ __launch_bounds__(256, 3) void gemm12_fused(const unsigned short* __restrict__ xbS,
                                                       const unsigned short* __restrict__ WeS,
                                                       const float* __restrict__ b_emb,
                                                       const unsigned short* __restrict__ W1S,
                                                       unsigned char* __restrict__ C8,  // [M,512] fp8
                                                       const float* __restrict__ a_src,
                                                       const float* __restrict__ a_dst,
                                                       float* __restrict__ as_out,
                                                       float* __restrict__ ad_out, int M) {
    __shared__ __align__(16) unsigned short h0s[128 * 132];
    __shared__ float sAl[128][2];

    int tid = threadIdx.x;
    int bx = blockIdx.x, by = blockIdx.y;   // bx in {0,1}
    int gm0 = by * 128;
    int w = tid >> 6, lane = tid & 63;
    int wrow = (w >> 1) * 64, wc = w & 1, wcol = wc * 64;
    int l15 = lane & 15, quad = lane >> 4;

    f32x4 acc[4][4];
#pragma unroll
    for (int i = 0; i < 4; i++)
#pragma unroll
        for (int j = 0; j < 4; j++) acc[i][j] = {0.f, 0.f, 0.f, 0.f};

    // ---- phase 1: emb GEMM (K=64), direct fragment loads ----
    const unsigned short* xA = xbS + (size_t)((gm0 + wrow) >> 4) * 1024 + quad * 128 + l15 * 8;
    const unsigned short* wB = WeS + (size_t)(wc * 4) * 1024 + quad * 128 + l15 * 8;
    const unsigned short* w1B0 = W1S + (size_t)(bx * 16 + wc * 4) * 2048 + quad * 128 + l15 * 8;
    const unsigned short* w1B1 = W1S + (size_t)(bx * 16 + 8 + wc * 4) * 2048 + quad * 128 + l15 * 8;
#pragma unroll
    for (int ks = 0; ks < 2; ks++) {
        bf16x8 af[4], bfr[4];
#pragma unroll
        for (int i = 0; i < 4; i++) af[i] = *(const bf16x8*)(xA + i * 1024 + ks * 512);
#pragma unroll
        for (int j = 0; j < 4; j++) bfr[j] = *(const bf16x8*)(wB + j * 1024 + ks * 512);
#pragma unroll
        for (int i = 0; i < 4; i++)
#pragma unroll
            for (int j = 0; j < 4; j++)
                acc[i][j] = __builtin_amdgcn_mfma_f32_16x16x32_bf16(af[i], bfr[j], acc[i][j], 0, 0, 0);
    }

    // ---- hoist half-0 W1 fragment loads (hide under h0 epilogue + barrier) --
    bf16x8 wp[4][4];
#pragma unroll
    for (int ks = 0; ks < 4; ks++)
#pragma unroll
        for (int j = 0; j < 4; j++)
            wp[ks][j] = *(const bf16x8*)(w1B0 + j * 2048 + ks * 512);

    // ---- h0 = relu(acc + be) -> LDS (bf16), single barrier ----
#pragma unroll
    for (int j = 0; j < 4; j++) {
        int col = wcol + j * 16 + l15;
        float bv = b_emb[col];
#pragma unroll
        for (int i = 0; i < 4; i++) {
            int row = wrow + i * 16 + quad * 4;
#pragma unroll
            for (int r = 0; r < 4; r++) {
                float v = fmaxf(acc[i][j][r] + bv, 0.f);
                h0s[(row + r) * 132 + col] = f2b(v);
            }
        }
    }
#pragma unroll
    for (int i = 0; i < 4; i++)
#pragma unroll
        for (int j = 0; j < 4; j++) acc[i][j] = {0.f, 0.f, 0.f, 0.f};
    __syncthreads();

    // ---- half 0: h0 @ W1[:,cols bx*256..+127], A from LDS, B registers ----
#pragma unroll
    for (int ks = 0; ks < 4; ks++) {
        bf16x8 af[4];
#pragma unroll
        for (int i = 0; i < 4; i++)
            af[i] = *(const bf16x8*)&h0s[(wrow + i * 16 + l15) * 132 + ks * 32 + quad * 8];
#pragma unroll
        for (int i = 0; i < 4; i++)
#pragma unroll
            for (int j = 0; j < 4; j++)
                acc[i][j] = __builtin_amdgcn_mfma_f32_16x16x32_bf16(af[i], wp[ks][j], acc[i][j], 0, 0, 0);
    }

    // ---- issue half-1 W1 fragment loads now (hide under half-0 epilogue) ----
#pragma unroll
    for (int ks = 0; ks < 4; ks++)
#pragma unroll
        for (int j = 0; j < 4; j++)
            wp[ks][j] = *(const bf16x8*)(w1B1 + j * 2048 + ks * 512);

    // ---- half-0 epilogue: C8 + alpha (head hh0 = bx*2) ----
    {
        int gn0 = bx * 256;
        int hh = bx * 2;
#pragma unroll
        for (int i = 0; i < 4; i++) {
            int row = gm0 + wrow + i * 16 + quad * 4;
#pragma unroll
            for (int j = 0; j < 4; j++) {
                int col = gn0 + wcol + j * 16 + l15;
#pragma unroll
                for (int r = 0; r < 4; r++) {
                    int gr = row + r;
                    if (gr < M) C8[(size_t)gr * 512 + col] = f2fp8(acc[i][j][r]);
                }
            }
        }
        float as_c[4], ad_c[4];
#pragma unroll
        for (int j = 0; j < 4; j++) {
            int c = gn0 + wcol + j * 16 + l15;
            as_c[j] = a_src[c];
            ad_c[j] = a_dst[c];
        }
#pragma unroll
        for (int i = 0; i < 4; i++) {
#pragma unroll
            for (int r = 0; r < 4; r++) {
                float ps = 0.f, pd = 0.f;
#pragma unroll
                for (int j = 0; j < 4; j++) {
                    ps += acc[i][j][r] * as_c[j];
                    pd += acc[i][j][r] * ad_c[j];
                }
#pragma unroll
                for (int o = 1; o < 16; o <<= 1) {
                    ps += __shfl_xor(ps, o);
                    pd += __shfl_xor(pd, o);
                }
                if (wcol == 64 && l15 == 0) {
                    int lr = wrow + i * 16 + quad * 4 + r;
                    sAl[lr][0] = ps;
                    sAl[lr][1] = pd;
                }
            }
        }
        __syncthreads();
        if (wcol == 0) {
#pragma unroll
            for (int i = 0; i < 4; i++) {
#pragma unroll
                for (int r = 0; r < 4; r++) {
                    float ps = 0.f, pd = 0.f;
#pragma unroll
                    for (int j = 0; j < 4; j++) {
                        ps += acc[i][j][r] * as_c[j];
                        pd += acc[i][j][r] * ad_c[j];
                    }
#pragma unroll
                    for (int o = 1; o < 16; o <<= 1) {
                        ps += __shfl_xor(ps, o);
                        pd += __shfl_xor(pd, o);
                    }
                    if (l15 == 0) {
                        int lr = wrow + i * 16 + quad * 4 + r;
                        int gr = gm0 + lr;
                        if (gr < M) {
                            as_out[(size_t)gr * 4 + hh] = ps + sAl[lr][0];
                            ad_out[(size_t)gr * 4 + hh] = pd + sAl[lr][1];
                        }
                    }
                }
            }
        }
    }
    __syncthreads();   // sAl WAR: half-0 readers done before half-1 writers

    // ---- half 1: re-zero acc, MFMAs with wp (= half-1 frags) ----
#pragma unroll
    for (int i = 0; i < 4; i++)
#pragma unroll
        for (int j = 0; j < 4; j++) acc[i][j] = {0.f, 0.f, 0.f, 0.f};
#pragma unroll
    for (int ks = 0; ks < 4; ks++) {
        bf16x8 af[4];
#pragma unroll
        for (int i = 0; i < 4; i++)
            af[i] = *(const bf16x8*)&h0s[(wrow + i * 16 + l15) * 132 + ks * 32 + quad * 8];
#pragma unroll
        for (int i = 0; i < 4; i++)
#pragma unroll
            for (int j = 0; j < 4; j++)
                acc[i][j] = __builtin_amdgcn_mfma_f32_16x16x32_bf16(af[i], wp[ks][j], acc[i][j], 0, 0, 0);
    }

    // ---- half-1 epilogue: C8 + alpha (head hh1 = bx*2+1) ----
    {
        int gn0 = bx * 256 + 128;
        int hh = bx * 2 + 1;
#pragma unroll
        for (int i = 0; i < 4; i++) {
            int row = gm0 + wrow + i * 16 + quad * 4;
#pragma unroll
            for (int j = 0; j < 4; j++) {
                int col = gn0 + wcol + j * 16 + l15;
#pragma unroll
                for (int r = 0; r < 4; r++) {
                    int gr = row + r;
                    if (gr < M) C8[(size_t)gr * 512 + col] = f2fp8(acc[i][j][r]);
                }
            }
        }
        float as_c[4], ad_c[4];
#pragma unroll
        for (int j = 0; j < 4; j++) {
            int c = gn0 + wcol + j * 16 + l15;
            as_c[j] = a_src[c];
            ad_c[j] = a_dst[c];
        }
#pragma unroll
        for (int i = 0; i < 4; i++) {
#pragma unroll
            for (int r = 0; r < 4; r++) {
                float ps = 0.f, pd = 0.f;
#pragma unroll
                for (int j = 0; j < 4; j++) {
                    ps += acc[i][j][r] * as_c[j];
                    pd += acc[i][j][r] * ad_c[j];
                }
#pragma unroll
                for (int o = 1; o < 16; o <<= 1) {
                    ps += __shfl_xor(ps, o);
                    pd += __shfl_xor(pd, o);
                }
                if (wcol == 64 && l15 == 0) {
                    int lr = wrow + i * 16 + quad * 4 + r;
                    sAl[lr][0] = ps;
                    sAl[lr][1] = pd;
                }
            }
        }
        __syncthreads();
        if (wcol == 0) {
#pragma unroll
            for (int i = 0; i < 4; i++) {
#pragma unroll
                for (int r = 0; r < 4; r++) {
                    float ps = 0.f, pd = 0.f;
#pragma unroll
                    for (int j = 0; j < 4; j++) {
                        ps += acc[i][j][r] * as_c[j];
                        pd += acc[i][j][r] * ad_c[j];
                    }
#pragma unroll
                    for (int o = 1; o < 16; o <<= 1) {
                        ps += __shfl_xor(ps, o);
                        pd += __shfl_xor(pd, o);
                    }
                    if (l15 == 0) {
                        int lr = wrow + i * 16 + quad * 4 + r;
                        int gr = gm0 + lr;
                        if (gr < M) {
                            as_out[(size_t)gr * 4 + hh] = ps + sAl[lr][0];
                            ad_out[(size_t)gr * 4 + hh] = pd + sAl[lr][1];
                        }
                    }
                }
            }
        }
    }
}

// ---------------- MFMA bf16 NT GEMM (layer 2): fp8 out + fused alpha ----------
template <int ACT, int OFMT, int ALPHA, int H>
__global__ __launch_bounds__(256) void gemm_mfma_nt(const unsigned short* __restrict__ A,
                                                    const unsigned short* __restrict__ Bt,
                                                    const float* __restrict__ bias,
                                                    void* __restrict__ Cout,
                                                    const float* __restrict__ a_src,
                                                    const float* __restrict__ a_dst,
                                                    float* __restrict__ as_out,
                                                    float* __restrict__ ad_out,
                                                    int M, int N, int K) {
    __shared__ __align__(16) unsigned short As[128 * 40];
    __shared__ __align__(16) unsigned short Bs[128 * 40];
    __shared__ float sAl[128][2];
    int tid = threadIdx.x;
    int gm0 = blockIdx.y * 128, gn0 = blockIdx.x * 128;
    int w = tid >> 6, lane = tid & 63;
    int wrow = (w >> 1) * 64, wcol = (w & 1) * 64;
    int l15 = lane & 15, quad = lane >> 4;

    f32x4 acc[4][4];
#pragma unroll
    for (int i = 0; i < 4; i++)
#pragma unroll
        for (int j = 0; j < 4; j++) acc[i][j] = {0.f, 0.f, 0.f, 0.f};

    for (int k0 = 0; k0 < K; k0 += 32) {
#pragma unroll
        for (int rr = 0; rr < 2; rr++) {
            int lin = tid + rr * 256;
            int row = lin >> 2;
            int cg = (lin & 3) * 8;
            int grow = gm0 + row; if (grow >= M) grow = M - 1;
            uint4 va = *(const uint4*)&A[(size_t)grow * K + k0 + cg];
            *(uint4*)&As[row * 40 + cg] = va;
            uint4 vb = *(const uint4*)&Bt[(size_t)(gn0 + row) * K + k0 + cg];
            *(uint4*)&Bs[row * 40 + cg] = vb;
        }
        __syncthreads();
        bf16x8 af[4], bfr[4];
#pragma unroll
        for (int i = 0; i < 4; i++) {
            af[i]  = *(const bf16x8*)&As[(wrow + i * 16 + l15) * 40 + quad * 8];
            bfr[i] = *(const bf16x8*)&Bs[(wcol + i * 16 + l15) * 40 + quad * 8];
        }
#pragma unroll
        for (int i = 0; i < 4; i++)
#pragma unroll
            for (int j = 0; j < 4; j++)
                acc[i][j] = __builtin_amdgcn_mfma_f32_16x16x32_bf16(af[i], bfr[j], acc[i][j], 0, 0, 0);
        __syncthreads();
    }

    if (OFMT == 0) {
        unsigned short* C = (unsigned short*)Cout;
#pragma unroll
        for (int i = 0; i < 4; i++) {
            int row = gm0 + wrow + i * 16 + quad * 4;
#pragma unroll
            for (int j = 0; j < 4; j++) {
                int col = gn0 + wcol + j * 16 + l15;
                float bv = bias ? bias[col] : 0.f;
#pragma unroll
                for (int r = 0; r < 4; r++) {
                    int gr = row + r;
                    if (gr < M) {
                        float v = acc[i][j][r] + bv;
                        if (ACT == 1) v = fmaxf(v, 0.f);
                        C[(size_t)gr * N + col] = f2b(v);
                    }
                }
            }
        }
    } else {
        unsigned char* C8 = (unsigned char*)Cout;
#pragma unroll
        for (int i = 0; i < 4; i++) {
            int row = gm0 + wrow + i * 16 + quad * 4;
#pragma unroll
            for (int j = 0; j < 4; j++) {
                int col = gn0 + wcol + j * 16 + l15;
#pragma unroll
                for (int r = 0; r < 4; r++) {
                    int gr = row + r;
                    if (gr < M) C8[(size_t)gr * N + col] = f2fp8(acc[i][j][r]);
                }
            }
        }
    }

    if (ALPHA) {
        int hh = blockIdx.x;
        float as_c[4], ad_c[4];
#pragma unroll
        for (int j = 0; j < 4; j++) {
            int c = gn0 + wcol + j * 16 + l15;
            as_c[j] = a_src[c];
            ad_c[j] = a_dst[c];
        }
#pragma unroll
        for (int i = 0; i < 4; i++) {
#pragma unroll
            for (int r = 0; r < 4; r++) {
                float ps = 0.f, pd = 0.f;
#pragma unroll
                for (int j = 0; j < 4; j++) {
                    ps += acc[i][j][r] * as_c[j];
                    pd += acc[i][j][r] * ad_c[j];
                }
#pragma unroll
                for (int o = 1; o < 16; o <<= 1) {
                    ps += __shfl_xor(ps, o);
                    pd += __shfl_xor(pd, o);
                }
                if (wcol == 64 && l15 == 0) {
                    int lr = wrow + i * 16 + quad * 4 + r;
                    sAl[lr][0] = ps;
                    sAl[lr][1] = pd;
                }
            }
        }
        __syncthreads();
        if (wcol == 0) {
#pragma unroll
            for (int i = 0; i < 4; i++) {
#pragma unroll
                for (int r = 0; r < 4; r++) {
                    float ps = 0.f, pd = 0.f;
#pragma unroll
                    for (int j = 0; j < 4; j++) {
                        ps += acc[i][j][r] * as_c[j];
                        pd += acc[i][j][r] * ad_c[j];
                    }
#pragma unroll
                    for (int o = 1; o < 16; o <<= 1) {
                        ps += __shfl_xor(ps, o);
                        pd += __shfl_xor(pd, o);
                    }
                    if (l15 == 0) {
                        int lr = wrow + i * 16 + quad * 4 + r;
                        int gr = gm0 + lr;
                        if (gr < M) {
                            as_out[(size_t)gr * H + hh] = ps + sAl[lr][0];
                            ad_out[(size_t)gr * H + hh] = pd + sAl[lr][1];
                        }
                    }
                }
            }
        }
    }
}

// ---------------- GAT agg L1 (H=4): 1 wave/node, fp8 gather, 4-edge MLP -------
// 4-edge unroll is the measured sweet spot (VGPR 36 / occ 59%); 8-deep regressed.
// r15: packed f32x2 accumulators — cvt_pk_f32_fp8 pairs feed v_pk_fma_f32.
__global__ __launch_bounds__(256) void gat_agg_l1(const unsigned* __restrict__ hq,
                                                  const float4* __restrict__ as4,
                                                  const float4* __restrict__ ad4,
                                                  const int* __restrict__ rowptr,
                                                  const int* __restrict__ esrc,
                                                  const float* __restrict__ bias,
                                                  unsigned short* __restrict__ out, int N) {
    __shared__ float wlds_all[4][256];
    int w = threadIdx.x >> 6, lane = threadIdx.x & 63;
    int n = blockIdx.x * 4 + w;
    if (n >= N) return;
    float* wlds = wlds_all[w];
    int2 rp = *(const int2*)&rowptr[n];    // one 8B load: begin, end
    int begin = rp.x, deg = rp.y - rp.x;
    float4 adn = ad4[n];

    int s_l0 = 0;
    float4 e0 = {-3.4e38f, -3.4e38f, -3.4e38f, -3.4e38f};
    if (lane < deg) {
        s_l0 = esrc[begin + lane];
        float4 u = as4[s_l0];
        e0.x = LRELU(u.x + adn.x); e0.y = LRELU(u.y + adn.y);
        e0.z = LRELU(u.z + adn.z); e0.w = LRELU(u.w + adn.w);
    }
    float4 m = e0;
    for (int base = 64; base < deg; base += 64) {
        int j = base + lane;
        if (j < deg) {
            float4 u = as4[esrc[begin + j]];
            m.x = fmaxf(m.x, LRELU(u.x + adn.x)); m.y = fmaxf(m.y, LRELU(u.y + adn.y));
            m.z = fmaxf(m.z, LRELU(u.z + adn.z)); m.w = fmaxf(m.w, LRELU(u.w + adn.w));
        }
    }
#pragma unroll
    for (int o = 32; o >= 1; o >>= 1) {
        m.x = fmaxf(m.x, __shfl_xor(m.x, o));
        m.y = fmaxf(m.y, __shfl_xor(m.y, o));
        m.z = fmaxf(m.z, __shfl_xor(m.z, o));
        m.w = fmaxf(m.w, __shfl_xor(m.w, o));
    }
    float4 s4 = {0.f, 0.f, 0.f, 0.f};
    if (lane < deg) {
        s4.x = __expf(e0.x - m.x); s4.y = __expf(e0.y - m.y);
        s4.z = __expf(e0.z - m.z); s4.w = __expf(e0.w - m.w);
    }
    for (int base = 64; base < deg; base += 64) {
        int j = base + lane;
        if (j < deg) {
            float4 u = as4[esrc[begin + j]];
            s4.x += __expf(LRELU(u.x + adn.x) - m.x); s4.y += __expf(LRELU(u.y + adn.y) - m.y);
            s4.z += __expf(LRELU(u.z + adn.z) - m.z); s4.w += __expf(LRELU(u.w + adn.w) - m.w);
        }
    }
#pragma unroll
    for (int o = 32; o >= 1; o >>= 1) {
        s4.x += __shfl_xor(s4.x, o); s4.y += __shfl_xor(s4.y, o);
        s4.z += __shfl_xor(s4.z, o); s4.w += __shfl_xor(s4.w, o);
    }
    float4 inv = {1.f / (s4.x + 1e-16f), 1.f / (s4.y + 1e-16f),
                  1.f / (s4.z + 1e-16f), 1.f / (s4.w + 1e-16f)};

    f32x2 acc2[4] = {};
    int h = lane >> 4;
#define ACC_E1(q, wgt) { \
    f32x2 wv = {wgt, wgt}; \
    acc2[0] += wv * __builtin_amdgcn_cvt_pk_f32_fp8((int)q.x, false); \
    acc2[1] += wv * __builtin_amdgcn_cvt_pk_f32_fp8((int)q.x, true);  \
    acc2[2] += wv * __builtin_amdgcn_cvt_pk_f32_fp8((int)q.y, false); \
    acc2[3] += wv * __builtin_amdgcn_cvt_pk_f32_fp8((int)q.y, true);  }

    for (int base = 0; base < deg; base += 64) {
        int j = base + lane;
        int len = min(64, deg - base);
        int s_l = s_l0;
        float4 e = e0;
        if (base > 0 && j < deg) {
            s_l = esrc[begin + j];
            float4 u = as4[s_l];
            e.x = LRELU(u.x + adn.x); e.y = LRELU(u.y + adn.y);
            e.z = LRELU(u.z + adn.z); e.w = LRELU(u.w + adn.w);
        }
        if (j < deg) {
            float4 wv4 = {__expf(e.x - m.x) * inv.x, __expf(e.y - m.y) * inv.y,
                          __expf(e.z - m.z) * inv.z, __expf(e.w - m.w) * inv.w};
            *(float4*)&wlds[lane * 4] = wv4;
        }
        int c = 0;
        for (; c + 4 <= len; c += 4) {
            int s0 = __builtin_amdgcn_readlane(s_l, c);
            int s1 = __builtin_amdgcn_readlane(s_l, c + 1);
            int s2 = __builtin_amdgcn_readlane(s_l, c + 2);
            int s3 = __builtin_amdgcn_readlane(s_l, c + 3);
            uint2 q0 = *((const uint2*)(hq + (size_t)s0 * 128) + lane);
            uint2 q1 = *((const uint2*)(hq + (size_t)s1 * 128) + lane);
            uint2 q2 = *((const uint2*)(hq + (size_t)s2 * 128) + lane);
            uint2 q3 = *((const uint2*)(hq + (size_t)s3 * 128) + lane);
            float w0 = wlds[c * 4 + h];
            float w1 = wlds[c * 4 + 4 + h];
            float w2 = wlds[c * 4 + 8 + h];
            float w3 = wlds[c * 4 + 12 + h];
            ACC_E1(q0, w0); ACC_E1(q1, w1); ACC_E1(q2, w2); ACC_E1(q3, w3);
        }
        for (; c < len; c++) {
            int s0 = __builtin_amdgcn_readlane(s_l, c);
            uint2 q0 = *((const uint2*)(hq + (size_t)s0 * 128) + lane);
            float w0 = wlds[c * 4 + h];
            ACC_E1(q0, w0);
        }
    }
#undef ACC_E1
    int f0 = lane * 8;
    unsigned pk[4];
#pragma unroll
    for (int k = 0; k < 4; k++) {
        float v0 = acc2[k].x + bias[f0 + 2 * k];
        float v1 = acc2[k].y + bias[f0 + 2 * k + 1];
        v0 = v0 > 0.f ? v0 : (__expf(v0) - 1.f);
        v1 = v1 > 0.f ? v1 : (__expf(v1) - 1.f);
        pk[k] = (unsigned)f2b(v0) | ((unsigned)f2b(v1) << 16);
    }
    uint4 pv = {pk[0], pk[1], pk[2], pk[3]};
    *((uint4*)(out + (size_t)n * 512) + lane) = pv;
}

// ---------------- GAT agg L2 (H=1): 1 wave/node, fp8 gather, 4-edge MLP -------
// r15: packed f32x2 accumulator.
__global__ __launch_bounds__(256) void gat_agg_l2(const unsigned char* __restrict__ hq,
                                                  const float* __restrict__ as,
                                                  const float* __restrict__ ad,
                                                  const int* __restrict__ rowptr,
                                                  const int* __restrict__ esrc,
                                                  const float* __restrict__ bias,
                                                  float* __restrict__ out, int N) {
    int w = threadIdx.x >> 6, lane = threadIdx.x & 63;
    int n = blockIdx.x * 4 + w;
    if (n >= N) return;
    int2 rp = *(const int2*)&rowptr[n];
    int begin = rp.x, deg = rp.y - rp.x;
    float adn = ad[n];

    int s_l0 = 0;
    float e0 = -3.4e38f;
    if (lane < deg) {
        s_l0 = esrc[begin + lane];
        e0 = LRELU(as[s_l0] + adn);
    }
    float m = e0;
    for (int base = 64; base < deg; base += 64) {
        int j = base + lane;
        if (j < deg) m = fmaxf(m, LRELU(as[esrc[begin + j]] + adn));
    }
#pragma unroll
    for (int o = 32; o >= 1; o >>= 1) m = fmaxf(m, __shfl_xor(m, o));

    float s = (lane < deg) ? __expf(e0 - m) : 0.f;
    for (int base = 64; base < deg; base += 64) {
        int j = base + lane;
        if (j < deg) s += __expf(LRELU(as[esrc[begin + j]] + adn) - m);
    }
#pragma unroll
    for (int o = 32; o >= 1; o >>= 1) s += __shfl_xor(s, o);
    float inv = 1.f / (s + 1e-16f);

    f32x2 acc2 = {0.f, 0.f};
    for (int base = 0; base < deg; base += 64) {
        int j = base + lane;
        int len = min(64, deg - base);
        int s_l = s_l0;
        float e = e0;
        if (base > 0 && j < deg) {
            s_l = esrc[begin + j];
            e = LRELU(as[s_l] + adn);
        }
        float w_l = (j < deg) ? __expf(e - m) * inv : 0.f;
        int c = 0;
        for (; c + 4 <= len; c += 4) {
            int sp0 = __builtin_amdgcn_readlane(s_l, c);
            int sp1 = __builtin_amdgcn_readlane(s_l, c + 1);
            int sp2 = __builtin_amdgcn_readlane(s_l, c + 2);
            int sp3 = __builtin_amdgcn_readlane(s_l, c + 3);
            unsigned short u0 = *((const unsigned short*)(hq + (size_t)sp0 * 128) + lane);
            unsigned short u1 = *((const unsigned short*)(hq + (size_t)sp1 * 128) + lane);
            unsigned short u2 = *((const unsigned short*)(hq + (size_t)sp2 * 128) + lane);
            unsigned short u3 = *((const unsigned short*)(hq + (size_t)sp3 * 128) + lane);
            float w0 = rl_f(w_l, c), w1 = rl_f(w_l, c + 1);
            float w2 = rl_f(w_l, c + 2), w3 = rl_f(w_l, c + 3);
            f32x2 wv0 = {w0, w0}, wv1 = {w1, w1}, wv2 = {w2, w2}, wv3 = {w3, w3};
            acc2 += wv0 * __builtin_amdgcn_cvt_pk_f32_fp8((int)u0, false);
            acc2 += wv1 * __builtin_amdgcn_cvt_pk_f32_fp8((int)u1, false);
            acc2 += wv2 * __builtin_amdgcn_cvt_pk_f32_fp8((int)u2, false);
            acc2 += wv3 * __builtin_amdgcn_cvt_pk_f32_fp8((int)u3, false);
        }
        for (; c < len; c++) {
            int sp0 = __builtin_amdgcn_readlane(s_l, c);
            float w0 = rl_f(w_l, c);
            unsigned short u0 = *((const unsigned short*)(hq + (size_t)sp0 * 128) + lane);
            f32x2 wv0 = {w0, w0};
            acc2 += wv0 * __builtin_amdgcn_cvt_pk_f32_fp8((int)u0, false);
        }
    }
    float v0 = acc2.x + bias[lane * 2];
    float v1 = acc2.y + bias[lane * 2 + 1];
    v0 = v0 > 0.f ? v0 : (__expf(v0) - 1.f);
    v1 = v1 > 0.f ? v1 : (__expf(v1) - 1.f);
    float2 pv = {v0, v1};
    *(float2*)&out[(size_t)n * 128 + lane * 2] = pv;
}

// ---------------- mean pool + final GEMV (fused via done-counter) -------------
__global__ __launch_bounds__(256) void pool_final_kernel(const float* __restrict__ o2,
                                                         float* __restrict__ pool,
                                                         int* __restrict__ done,
                                                         const float* __restrict__ Wout,
                                                         const float* __restrict__ bout,
                                                         float* __restrict__ out,
                                                         int N, int nblocks, float invN) {
    __shared__ float4 sred[256];
    int f4 = threadIdx.x & 31;
    int r = blockIdx.x * 256 + (threadIdx.x >> 5);
    float4 acc = {0.f, 0.f, 0.f, 0.f};
    for (int i = 0; i < 32; i++, r += 8) {
        if (r < N) {
            float4 v = *(const float4*)&o2[(size_t)r * 128 + f4 * 4];
            acc.x += v.x; acc.y += v.y; acc.z += v.z; acc.w += v.w;
        }
    }
    sred[threadIdx.x] = acc;
    __syncthreads();
    if (threadIdx.x < 32) {
        float4 t = sred[threadIdx.x];
#pragma unroll
        for (int k = 1; k < 8; k++) {
            float4 u = sred[threadIdx.x + 32 * k];
            t.x += u.x; t.y += u.y; t.z += u.z; t.w += u.w;
        }
        atomicAdd(&pool[f4 * 4 + 0], t.x);
        atomicAdd(&pool[f4 * 4 + 1], t.y);
        atomicAdd(&pool[f4 * 4 + 2], t.z);
        atomicAdd(&pool[f4 * 4 + 3], t.w);
    }
    __threadfence();
    __shared__ int isLast;
    if (threadIdx.x == 0) isLast = (atomicAdd(done, 1) == nblocks - 1);
    __syncthreads();
    if (isLast) {
        __shared__ float spool[128];
        if (threadIdx.x < 128) spool[threadIdx.x] = atomicAdd(&pool[threadIdx.x], 0.f);
        __syncthreads();
        int o = threadIdx.x;
        float a = 0.f;
        for (int k = 0; k < 128; k++) a += spool[k] * Wout[k * 256 + o];
        out[o] = a * invN + bout[o];
    }
}

// ---------------- launch ------------------------------------------------------
extern "C" void kernel_launch(void* const* d_in, const int* in_sizes, int n_in,
                              void* d_out, int out_size, void* d_ws, size_t ws_size,
                              hipStream_t stream) {
    const float* x      = (const float*)d_in[0];
    const int*   ei     = (const int*)d_in[1];
    const float* W_emb  = (const float*)d_in[2];
    const float* b_emb  = (const float*)d_in[3];
    const float* W1     = (const float*)d_in[4];
    const float* a1_src = (const float*)d_in[5];
    const float* a1_dst = (const float*)d_in[6];
    const float* b1     = (const float*)d_in[7];
    const float* W2     = (const float*)d_in[8];
    const float* a2_src = (const float*)d_in[9];
    const float* a2_dst = (const float*)d_in[10];
    const float* b2     = (const float*)d_in[11];
    const float* W_out  = (const float*)d_in[12];
    const float* b_out  = (const float*)d_in[13];
    float* out = (float*)d_out;

    const int N = in_sizes[0] / 64;   // 25000
    const int E = in_sizes[1] / 2;    // 400000
    const int Etot = E + N;
    const int nb = (N + 255) / 256;   // 98 blocks — must stay <= CU count (lookback co-residency)
    const int mtiles = (N + 127) / 128;   // 196
    const int nrb = mtiles * 8;           // 16-row fragment blocks incl. tail

    char* ws = (char*)d_ws;
    size_t off = 0;
    auto alloc = [&](size_t bytes) -> void* {
        void* p = ws + off;
        off = (off + bytes + 255) & ~(size_t)255;
        return p;
    };
    typedef unsigned short u16;
    u16* xbS   = (u16*)alloc((size_t)nrb * 1024 * 2);     // frag-swizzled x (bf16)
    u16* WeS   = (u16*)alloc((size_t)8 * 1024 * 2);       // frag-swizzled We
    u16* W1S   = (u16*)alloc((size_t)32 * 2048 * 2);      // frag-swizzled W1
    u16* W2T   = (u16*)alloc((size_t)128 * 512 * 2);
    unsigned char* h1q = (unsigned char*)alloc((size_t)N * 512);   // fp8
    u16* o1b   = (u16*)alloc((size_t)N * 512 * 2);
    unsigned char* h2q = (unsigned char*)alloc((size_t)N * 128);   // fp8
    float* o2  = (float*)alloc((size_t)N * 128 * 4);
    float* as1 = (float*)alloc((size_t)N * 4 * 4);
    float* ad1 = (float*)alloc((size_t)N * 4 * 4);
    float* as2 = (float*)alloc((size_t)N * 4);
    float* ad2 = (float*)alloc((size_t)N * 4);
    float* pool = (float*)alloc(128 * 4);
    int* done   = (int*)alloc(256);
    int* rowptr = (int*)alloc((size_t)(N + 1) * 4);
    int* deg    = (int*)alloc((size_t)N * 4);
    int* cursor = (int*)alloc((size_t)N * 4);
    int* sagg   = (int*)alloc((size_t)nb * 4);
    int* sflg   = (int*)alloc((size_t)nb * 4);
    int* esrc   = (int*)alloc((size_t)Etot * 4);

    const int blocksE = (Etot + 255) / 256;
    const int Nx = N * 64;
    const int prepElems = Nx + 64 * 128 + 128 * 512 + 512 * 128;
    const int prepBlocks = (prepElems + 255) / 256;

    // K1: zero deg/pool/done + scan flags & aggs
    int zn = N + 128 + 1 + 2 * nb;
    zero_kernel<<<(zn + 255) / 256, 256, 0, stream>>>(deg, pool, done, sflg, sagg, N, nb);

    // K2: degree histogram (atomics) ∥ swizzled bf16 conversions
    degcount_prep<<<blocksE + prepBlocks, 256, 0, stream>>>(ei, E, N, deg, blocksE,
                                                            x, W_emb, W1, W2,
                                                            xbS, WeS, W1S, W2T, Nx);

    // K3: single-dispatch exclusive scan (decoupled lookback) + cursor seed
    scan_lookback<<<nb, 256, 0, stream>>>(deg, rowptr, cursor, sagg, sflg, N, nb);

    // K4: CSR scatter (tiny, full occupancy)
    scatter_kernel<<<blocksE, 256, 0, stream>>>(ei, E, N, cursor, esrc);

    // K5: fused GEMM1+2 (h1pre = relu(x@We+be)@W1, fp8 + alpha1), 2-col-split
    gemm12_fused<<<dim3(2, mtiles), 256, 0, stream>>>(xbS, WeS, b_emb, W1S, h1q,
                                                      a1_src, a1_dst, as1, ad1, N);

    // K6: layer-1 aggregation (logits on the fly, fp8 gather)
    gat_agg_l1<<<(N + 3) / 4, 256, 0, stream>>>((const unsigned*)h1q, (const float4*)as1,
                                                (const float4*)ad1, rowptr, esrc, b1, o1b, N);

    // K7: h2pre = o1 @ W2  [N,128] fp8 + fused alpha2 (r16 reverted)
    gemm_mfma_nt<0, 1, 1, 1><<<dim3(1, mtiles), 256, 0, stream>>>(
        o1b, W2T, nullptr, h2q, a2_src, a2_dst, as2, ad2, N, 128, 512);

    // K8: layer-2 aggregation
    gat_agg_l2<<<(N + 3) / 4, 256, 0, stream>>>(h2q, as2, ad2, rowptr, esrc, b2, o2, N);

    // K9: mean pool + final GEMV
    int npb = (N + 255) / 256;
    pool_final_kernel<<<npb, 256, 0, stream>>>(o2, pool, done, W_out, b_out, out,
                                               N, npb, 1.f / (float)N);
}

// Round 11
// 268.379 us; speedup vs baseline: 1.0222x; 1.0081x over previous
//
#include <hip/hip_runtime.h>
#include <hip/hip_bf16.h>

// N=25000, E=400000 (+N self loops), F_IN=64, HID=128, HEADS=4, OUT=256
// bf16 MFMA GEMMs (embed GEMM fused into layer-1 GEMM via LDS round-trip);
// node-feature gather operands stored fp8(e4m3); alpha dots fused into GEMM
// epilogues (f32-exact); edge logits computed on the fly in agg kernels.
// TUNING LOG (measured):
//  - grid.sync ~30us/barrier on gfx950 — never fuse cheap kernels with it (r5).
//  - agg gather unroll: 4-deep = VGPR 36 / occ 59% / best; 8-deep REGRESSION (r9).
//  - Harness ws-poison fill (~44us, 268MB) is a fixed floor in the trace.
//  - Noise calibration: per-kernel +-3us (agg_l1 42..45 same code), total +-4us.
//    Changes with <8us expected value are not reliably measurable.
//  - r10: degcount∥prep + lookback scan + cursor-seed GOOD; scatter∥gemm12
//    fusion BAD (scatter blocks inherited 45KB LDS).
//  - r11/r12: unfuse scatter GOOD. Direct-fragment loads REGRESS if they sit
//    after a barrier (serial L2 chain).
//  - r13/r14 WIN: register-hoist W1 fragment loads above the barrier.
//    gemm12 48-54 -> <44. Total 268.6 -> 265.4 (best).
//  - r15 NEUTRAL: packed f32x2 agg accumulators. Keep.
//  - r16 REGRESSION (+5us): rewrote never-measured gemm_mfma_nt as zero-LDS
//    gemm2_direct. Lesson: don't rewrite unmeasured kernels. Reverted r17.
//  - r17 NEUTRAL-within-noise (270.6): gemm12 2-col-split (strictly less
//    work: phase-1 redundancy 4x->2x, xbS fetch halved). Keep.
//  - r19: gemm_mfma_nt register double-buffer. Its 16 K-steps issue global
//    loads AFTER the tail barrier -> 16x exposed L2 latency at ~1 wave/SIMD
//    (196 blocks). Prologue-load tile 0; per step: regs->LDS, barrier, issue
//    NEXT tile loads (overlap ds_read+MFMA+barrier). r13's proven pattern.
//  - r20 (this round): identical resubmit of r19 — GPUAcquisitionTimeout
//    (broker capacity). Kernel never executed; no data, no changes.

#define LRELU(x) ((x) > 0.f ? (x) : 0.2f * (x))

typedef short bf16x8 __attribute__((ext_vector_type(8)));
typedef float f32x4 __attribute__((ext_vector_type(4)));
typedef float f32x2 __attribute__((ext_vector_type(2)));

static __device__ __forceinline__ unsigned short f2b(float f) {
    union { float f; unsigned u; } x; x.f = f;
    unsigned r = x.u + 0x7fff + ((x.u >> 16) & 1);
    return (unsigned short)(r >> 16);
}
static __device__ __forceinline__ float rl_f(float v, int c) {
    return __int_as_float(__builtin_amdgcn_readlane(__float_as_int(v), c));
}
static __device__ __forceinline__ unsigned char f2fp8(float v) {
    int p = __builtin_amdgcn_cvt_pk_fp8_f32(v, v, 0, false);
    return (unsigned char)(p & 0xff);
}

// ---------------- zero scratch (deg + pool + done + scan flags/aggs) ----------
__global__ void zero_kernel(int* __restrict__ deg, float* __restrict__ pool,
                            int* __restrict__ done, int* __restrict__ flg,
                            int* __restrict__ agg, int N, int nb) {
    int i = blockIdx.x * blockDim.x + threadIdx.x;
    if (i < N) { deg[i] = 0; return; }
    i -= N;
    if (i < 128) { pool[i] = 0.f; return; }
    i -= 128;
    if (i == 0) { *done = 0; return; }
    i -= 1;
    if (i < nb) { flg[i] = 0; return; }
    i -= nb;
    if (i < nb) agg[i] = 0;
}

// ---------------- fused: degree count (atomics) ∥ prep conversions ------------
// prep writes MFMA-fragment-swizzled bf16 layouts so the GEMM loads fragments
// directly from global (coalesced 1KiB per wave-fragment):
//   xbS idx(r,k)  = (r>>4)*1024 + (k>>3)*128 + (r&15)*8 + (k&7)      [r<25000,k<64]
//   WeS idx(n,k)  = (n>>4)*1024 + (k>>5)*512 + ((k>>3)&3)*128 + (n&15)*8 + (k&7)
//   W1S idx(n,k)  = (n>>4)*2048 + (k>>5)*512 + ((k>>3)&3)*128 + (n&15)*8 + (k&7)
__global__ void degcount_prep(const int* __restrict__ ei, int E, int N,
                              int* __restrict__ deg, int blocksE,
                              const float* __restrict__ x, const float* __restrict__ We,
                              const float* __restrict__ W1, const float* __restrict__ W2,
                              unsigned short* __restrict__ xbS, unsigned short* __restrict__ WeS,
                              unsigned short* __restrict__ W1S, unsigned short* __restrict__ W2T,
                              int Nx) {
    if ((int)blockIdx.x < blocksE) {
        int i = blockIdx.x * blockDim.x + threadIdx.x;
        if (i < E) atomicAdd(&deg[ei[E + i]], 1);
        else if (i < E + N) atomicAdd(&deg[i - E], 1);
        return;
    }
    int i = (blockIdx.x - blocksE) * blockDim.x + threadIdx.x;
    if (i < Nx) {
        int r = i >> 6, k = i & 63;
        xbS[(r >> 4) * 1024 + (k >> 3) * 128 + (r & 15) * 8 + (k & 7)] = f2b(x[i]);
        return;
    }
    i -= Nx;
    if (i < 64 * 128) {
        int k = i >> 7, n = i & 127;
        WeS[(n >> 4) * 1024 + (k >> 5) * 512 + ((k >> 3) & 3) * 128 + (n & 15) * 8 + (k & 7)] = f2b(We[i]);
        return;
    }
    i -= 64 * 128;
    if (i < 128 * 512) {
        int k = i >> 9, n = i & 511;
        W1S[(n >> 4) * 2048 + (k >> 5) * 512 + ((k >> 3) & 3) * 128 + (n & 15) * 8 + (k & 7)] = f2b(W1[i]);
        return;
    }
    i -= 128 * 512;
    if (i < 512 * 128) { int k = i >> 7, n = i & 127; W2T[n * 512 + k] = f2b(W2[i]); return; }
}

// ---------------- single-dispatch exclusive scan (decoupled lookback) ---------
// nb = 98 blocks <= 256 CUs -> all blocks co-resident, spin cannot deadlock.
// Agent-scope release/acquire handles cross-XCD L2 non-coherence. Seeds
// cursor[i] = rowptr[i] so scatter needs only atomicAdd(&cursor[d],1).
__global__ __launch_bounds__(256) void scan_lookback(const int* __restrict__ deg,
                                                     int* __restrict__ rowptr,
                                                     int* __restrict__ cursor,
                                                     int* __restrict__ agg,
                                                     int* __restrict__ flg,
                                                     int N, int nb) {
    __shared__ int sd[256];
    __shared__ int soff;
    int t = threadIdx.x, b = blockIdx.x;
    int i = b * 256 + t;
    int d = (i < N) ? deg[i] : 0;
    sd[t] = d;
    __syncthreads();
    for (int off = 1; off < 256; off <<= 1) {
        int v = (t >= off) ? sd[t - off] : 0;
        __syncthreads();
        sd[t] += v;
        __syncthreads();
    }
    int incl = sd[t];
    int btot = sd[255];
    if (t == 0) {
        soff = 0;
        __hip_atomic_store(&agg[b], btot, __ATOMIC_RELAXED, __HIP_MEMORY_SCOPE_AGENT);
        __hip_atomic_store(&flg[b], 1, __ATOMIC_RELEASE, __HIP_MEMORY_SCOPE_AGENT);
    }
    if (b > 0 && t < 64) {
        int acc = 0;
        for (int p = t; p < b; p += 64) {
            while (__hip_atomic_load(&flg[p], __ATOMIC_ACQUIRE, __HIP_MEMORY_SCOPE_AGENT) == 0)
                __builtin_amdgcn_s_sleep(1);
            acc += __hip_atomic_load(&agg[p], __ATOMIC_RELAXED, __HIP_MEMORY_SCOPE_AGENT);
        }
#pragma unroll
        for (int o = 32; o >= 1; o >>= 1) acc += __shfl_xor(acc, o);
        if (t == 0) soff = acc;
    }
    __syncthreads();
    int off = soff;
    int excl = off + incl - d;
    if (i < N) { rowptr[i] = excl; cursor[i] = excl; }
    if (b == nb - 1 && t == 255) rowptr[N] = off + btot;
}

// ---------------- CSR scatter (tiny, zero LDS, full occupancy) ----------------
__global__ void scatter_kernel(const int* __restrict__ ei, int E, int N,
                               int* __restrict__ cursor, int* __restrict__ esrc) {
    int i = blockIdx.x * blockDim.x + threadIdx.x;
    int s, d;
    if (i < E) { s = ei[i]; d = ei[E + i]; }
    else if (i < E + N) { s = i - E; d = s; }
    else return;
    int pos = atomicAdd(&cursor[d], 1);
    esrc[pos] = s;
}

// ---------------- fused GEMM1+2: h1 = relu(x@We+be)@W1, fp8 out + alpha -------
// r17: 2-way column split. Block (bx,by) computes rows by*128..+127, columns
// bx*256..+255 as two 128-col halves. Phase-1 emb GEMM computed once per
// block (2x total redundancy instead of 4x). Half-0 W1 frags hoisted
// pre-barrier (r13 rule); half-1 frags issued after half-0 MFMAs so their
// latency hides under half-0's C8+alpha epilogue.
__global__ __launch_bounds__(256, 3) void gemm12_fused(const unsigned short* __restrict__ xbS,
                                                       const unsigned short* __restrict__ WeS,
                                                       const float* __restrict__ b_emb,
                                                       const unsigned short* __restrict__ W1S,
                                                       unsigned char* __restrict__ C8,  // [M,512] fp8
                                                       const float* __restrict__ a_src,
                                                       const float* __restrict__ a_dst,
                                                       float* __restrict__ as_out,
                                                       float* __restrict__ ad_out, int M) {
    __shared__ __align__(16) unsigned short h0s[128 * 132];
    __shared__ float sAl[128][2];

    int tid = threadIdx.x;
    int bx = blockIdx.x, by = blockIdx.y;   // bx in {0,1}
    int gm0 = by * 128;
    int w = tid >> 6, lane = tid & 63;
    int wrow = (w >> 1) * 64, wc = w & 1, wcol = wc * 64;
    int l15 = lane & 15, quad = lane >> 4;

    f32x4 acc[4][4];
#pragma unroll
    for (int i = 0; i < 4; i++)
#pragma unroll
        for (int j = 0; j < 4; j++) acc[i][j] = {0.f, 0.f, 0.f, 0.f};

    // ---- phase 1: emb GEMM (K=64), direct fragment loads ----
    const unsigned short* xA = xbS + (size_t)((gm0 + wrow) >> 4) * 1024 + quad * 128 + l15 * 8;
    const unsigned short* wB = WeS + (size_t)(wc * 4) * 1024 + quad * 128 + l15 * 8;
    const unsigned short* w1B0 = W1S + (size_t)(bx * 16 + wc * 4) * 2048 + quad * 128 + l15 * 8;
    const unsigned short* w1B1 = W1S + (size_t)(bx * 16 + 8 + wc * 4) * 2048 + quad * 128 + l15 * 8;
#pragma unroll
    for (int ks = 0; ks < 2; ks++) {
        bf16x8 af[4], bfr[4];
#pragma unroll
        for (int i = 0; i < 4; i++) af[i] = *(const bf16x8*)(xA + i * 1024 + ks * 512);
#pragma unroll
        for (int j = 0; j < 4; j++) bfr[j] = *(const bf16x8*)(wB + j * 1024 + ks * 512);
#pragma unroll
        for (int i = 0; i < 4; i++)
#pragma unroll
            for (int j = 0; j < 4; j++)
                acc[i][j] = __builtin_amdgcn_mfma_f32_16x16x32_bf16(af[i], bfr[j], acc[i][j], 0, 0, 0);
    }

    // ---- hoist half-0 W1 fragment loads (hide under h0 epilogue + barrier) --
    bf16x8 wp[4][4];
#pragma unroll
    for (int ks = 0; ks < 4; ks++)
#pragma unroll
        for (int j = 0; j < 4; j++)
            wp[ks][j] = *(const bf16x8*)(w1B0 + j * 2048 + ks * 512);

    // ---- h0 = relu(acc + be) -> LDS (bf16), single barrier ----
#pragma unroll
    for (int j = 0; j < 4; j++) {
        int col = wcol + j * 16 + l15;
        float bv = b_emb[col];
#pragma unroll
        for (int i = 0; i < 4; i++) {
            int row = wrow + i * 16 + quad * 4;
#pragma unroll
            for (int r = 0; r < 4; r++) {
                float v = fmaxf(acc[i][j][r] + bv, 0.f);
                h0s[(row + r) * 132 + col] = f2b(v);
            }
        }
    }
#pragma unroll
    for (int i = 0; i < 4; i++)
#pragma unroll
        for (int j = 0; j < 4; j++) acc[i][j] = {0.f, 0.f, 0.f, 0.f};
    __syncthreads();

    // ---- half 0: h0 @ W1[:,cols bx*256..+127], A from LDS, B registers ----
#pragma unroll
    for (int ks = 0; ks < 4; ks++) {
        bf16x8 af[4];
#pragma unroll
        for (int i = 0; i < 4; i++)
            af[i] = *(const bf16x8*)&h0s[(wrow + i * 16 + l15) * 132 + ks * 32 + quad * 8];
#pragma unroll
        for (int i = 0; i < 4; i++)
#pragma unroll
            for (int j = 0; j < 4; j++)
                acc[i][j] = __builtin_amdgcn_mfma_f32_16x16x32_bf16(af[i], wp[ks][j], acc[i][j], 0, 0, 0);
    }

    // ---- issue half-1 W1 fragment loads now (hide under half-0 epilogue) ----
#pragma unroll
    for (int ks = 0; ks < 4; ks++)
#pragma unroll
        for (int j = 0; j < 4; j++)
            wp[ks][j] = *(const bf16x8*)(w1B1 + j * 2048 + ks * 512);

    // ---- half-0 epilogue: C8 + alpha (head hh0 = bx*2) ----
    {
        int gn0 = bx * 256;
        int hh = bx * 2;
#pragma unroll
        for (int i = 0; i < 4; i++) {
            int row = gm0 + wrow + i * 16 + quad * 4;
#pragma unroll
            for (int j = 0; j < 4; j++) {
                int col = gn0 + wcol + j * 16 + l15;
#pragma unroll
                for (int r = 0; r < 4; r++) {
                    int gr = row + r;
                    if (gr < M) C8[(size_t)gr * 512 + col] = f2fp8(acc[i][j][r]);
                }
            }
        }
        float as_c[4], ad_c[4];
#pragma unroll
        for (int j = 0; j < 4; j++) {
            int c = gn0 + wcol + j * 16 + l15;
            as_c[j] = a_src[c];
            ad_c[j] = a_dst[c];
        }
#pragma unroll
        for (int i = 0; i < 4; i++) {
#pragma unroll
            for (int r = 0; r < 4; r++) {
                float ps = 0.f, pd = 0.f;
#pragma unroll
                for (int j = 0; j < 4; j++) {
                    ps += acc[i][j][r] * as_c[j];
                    pd += acc[i][j][r] * ad_c[j];
                }
#pragma unroll
                for (int o = 1; o < 16; o <<= 1) {
                    ps += __shfl_xor(ps, o);
                    pd += __shfl_xor(pd, o);
                }
                if (wcol == 64 && l15 == 0) {
                    int lr = wrow + i * 16 + quad * 4 + r;
                    sAl[lr][0] = ps;
                    sAl[lr][1] = pd;
                }
            }
        }
        __syncthreads();
        if (wcol == 0) {
#pragma unroll
            for (int i = 0; i < 4; i++) {
#pragma unroll
                for (int r = 0; r < 4; r++) {
                    float ps = 0.f, pd = 0.f;
#pragma unroll
                    for (int j = 0; j < 4; j++) {
                        ps += acc[i][j][r] * as_c[j];
                        pd += acc[i][j][r] * ad_c[j];
                    }
#pragma unroll
                    for (int o = 1; o < 16; o <<= 1) {
                        ps += __shfl_xor(ps, o);
                        pd += __shfl_xor(pd, o);
                    }
                    if (l15 == 0) {
                        int lr = wrow + i * 16 + quad * 4 + r;
                        int gr = gm0 + lr;
                        if (gr < M) {
                            as_out[(size_t)gr * 4 + hh] = ps + sAl[lr][0];
                            ad_out[(size_t)gr * 4 + hh] = pd + sAl[lr][1];
                        }
                    }
                }
            }
        }
    }
    __syncthreads();   // sAl WAR: half-0 readers done before half-1 writers

    // ---- half 1: re-zero acc, MFMAs with wp (= half-1 frags) ----
#pragma unroll
    for (int i = 0; i < 4; i++)
#pragma unroll
        for (int j = 0; j < 4; j++) acc[i][j] = {0.f, 0.f, 0.f, 0.f};
#pragma unroll
    for (int ks = 0; ks < 4; ks++) {
        bf16x8 af[4];
#pragma unroll
        for (int i = 0; i < 4; i++)
            af[i] = *(const bf16x8*)&h0s[(wrow + i * 16 + l15) * 132 + ks * 32 + quad * 8];
#pragma unroll
        for (int i = 0; i < 4; i++)
#pragma unroll
            for (int j = 0; j < 4; j++)
                acc[i][j] = __builtin_amdgcn_mfma_f32_16x16x32_bf16(af[i], wp[ks][j], acc[i][j], 0, 0, 0);
    }

    // ---- half-1 epilogue: C8 + alpha (head hh1 = bx*2+1) ----
    {
        int gn0 = bx * 256 + 128;
        int hh = bx * 2 + 1;
#pragma unroll
        for (int i = 0; i < 4; i++) {
            int row = gm0 + wrow + i * 16 + quad * 4;
#pragma unroll
            for (int j = 0; j < 4; j++) {
                int col = gn0 + wcol + j * 16 + l15;
#pragma unroll
                for (int r = 0; r < 4; r++) {
                    int gr = row + r;
                    if (gr < M) C8[(size_t)gr * 512 + col] = f2fp8(acc[i][j][r]);
                }
            }
        }
        float as_c[4], ad_c[4];
#pragma unroll
        for (int j = 0; j < 4; j++) {
            int c = gn0 + wcol + j * 16 + l15;
            as_c[j] = a_src[c];
            ad_c[j] = a_dst[c];
        }
#pragma unroll
        for (int i = 0; i < 4; i++) {
#pragma unroll
            for (int r = 0; r < 4; r++) {
                float ps = 0.f, pd = 0.f;
#pragma unroll
                for (int j = 0; j < 4; j++) {
                    ps += acc[i][j][r] * as_c[j];
                    pd += acc[i][j][r] * ad_c[j];
                }
#pragma unroll
                for (int o = 1; o < 16; o <<= 1) {
                    ps += __shfl_xor(ps, o);
                    pd += __shfl_xor(pd, o);
                }
                if (wcol == 64 && l15 == 0) {
                    int lr = wrow + i * 16 + quad * 4 + r;
                    sAl[lr][0] = ps;
                    sAl[lr][1] = pd;
                }
            }
        }
        __syncthreads();
        if (wcol == 0) {
#pragma unroll
            for (int i = 0; i < 4; i++) {
#pragma unroll
                for (int r = 0; r < 4; r++) {
                    float ps = 0.f, pd = 0.f;
#pragma unroll
                    for (int j = 0; j < 4; j++) {
                        ps += acc[i][j][r] * as_c[j];
                        pd += acc[i][j][r] * ad_c[j];
                    }
#pragma unroll
                    for (int o = 1; o < 16; o <<= 1) {
                        ps += __shfl_xor(ps, o);
                        pd += __shfl_xor(pd, o);
                    }
                    if (l15 == 0) {
                        int lr = wrow + i * 16 + quad * 4 + r;
                        int gr = gm0 + lr;
                        if (gr < M) {
                            as_out[(size_t)gr * 4 + hh] = ps + sAl[lr][0];
                            ad_out[(size_t)gr * 4 + hh] = pd + sAl[lr][1];
                        }
                    }
                }
            }
        }
    }
}

// ---------------- MFMA bf16 NT GEMM (layer 2): fp8 out + fused alpha ----------
// r19: register double-buffer. Tile k0+32's global loads are issued right
// after the head barrier of step k0, overlapping ds_read+MFMA+tail barrier.
// Removes the 16x exposed L2 latency at ~1 wave/SIMD occupancy.
template <int ACT, int OFMT, int ALPHA, int H>
__global__ __launch_bounds__(256) void gemm_mfma_nt(const unsigned short* __restrict__ A,
                                                    const unsigned short* __restrict__ Bt,
                                                    const float* __restrict__ bias,
                                                    void* __restrict__ Cout,
                                                    const float* __restrict__ a_src,
                                                    const float* __restrict__ a_dst,
                                                    float* __restrict__ as_out,
                                                    float* __restrict__ ad_out,
                                                    int M, int N, int K) {
    __shared__ __align__(16) unsigned short As[128 * 40];
    __shared__ __align__(16) unsigned short Bs[128 * 40];
    __shared__ float sAl[128][2];
    int tid = threadIdx.x;
    int gm0 = blockIdx.y * 128, gn0 = blockIdx.x * 128;
    int w = tid >> 6, lane = tid & 63;
    int wrow = (w >> 1) * 64, wcol = (w & 1) * 64;
    int l15 = lane & 15, quad = lane >> 4;

    f32x4 acc[4][4];
#pragma unroll
    for (int i = 0; i < 4; i++)
#pragma unroll
        for (int j = 0; j < 4; j++) acc[i][j] = {0.f, 0.f, 0.f, 0.f};

    // per-thread staging addresses (constant across K-steps except k0)
    int lin0 = tid, lin1 = tid + 256;
    int row0 = lin0 >> 2, cg0 = (lin0 & 3) * 8;
    int row1 = lin1 >> 2, cg1 = (lin1 & 3) * 8;
    int ga0 = gm0 + row0; if (ga0 >= M) ga0 = M - 1;
    int ga1 = gm0 + row1; if (ga1 >= M) ga1 = M - 1;
    const unsigned short* pa0 = A + (size_t)ga0 * K + cg0;
    const unsigned short* pa1 = A + (size_t)ga1 * K + cg1;
    const unsigned short* pb0 = Bt + (size_t)(gn0 + row0) * K + cg0;
    const unsigned short* pb1 = Bt + (size_t)(gn0 + row1) * K + cg1;

    // prologue: load tile k0=0
    uint4 va0 = *(const uint4*)(pa0);
    uint4 va1 = *(const uint4*)(pa1);
    uint4 vb0 = *(const uint4*)(pb0);
    uint4 vb1 = *(const uint4*)(pb1);

    for (int k0 = 0; k0 < K; k0 += 32) {
        *(uint4*)&As[row0 * 40 + cg0] = va0;
        *(uint4*)&As[row1 * 40 + cg1] = va1;
        *(uint4*)&Bs[row0 * 40 + cg0] = vb0;
        *(uint4*)&Bs[row1 * 40 + cg1] = vb1;
        __syncthreads();
        if (k0 + 32 < K) {       // issue NEXT tile loads; overlap MFMA below
            va0 = *(const uint4*)(pa0 + k0 + 32);
            va1 = *(const uint4*)(pa1 + k0 + 32);
            vb0 = *(const uint4*)(pb0 + k0 + 32);
            vb1 = *(const uint4*)(pb1 + k0 + 32);
        }
        bf16x8 af[4], bfr[4];
#pragma unroll
        for (int i = 0; i < 4; i++) {
            af[i]  = *(const bf16x8*)&As[(wrow + i * 16 + l15) * 40 + quad * 8];
            bfr[i] = *(const bf16x8*)&Bs[(wcol + i * 16 + l15) * 40 + quad * 8];
        }
#pragma unroll
        for (int i = 0; i < 4; i++)
#pragma unroll
            for (int j = 0; j < 4; j++)
                acc[i][j] = __builtin_amdgcn_mfma_f32_16x16x32_bf16(af[i], bfr[j], acc[i][j], 0, 0, 0);
        __syncthreads();
    }

    if (OFMT == 0) {
        unsigned short* C = (unsigned short*)Cout;
#pragma unroll
        for (int i = 0; i < 4; i++) {
            int row = gm0 + wrow + i * 16 + quad * 4;
#pragma unroll
            for (int j = 0; j < 4; j++) {
                int col = gn0 + wcol + j * 16 + l15;
                float bv = bias ? bias[col] : 0.f;
#pragma unroll
                for (int r = 0; r < 4; r++) {
                    int gr = row + r;
                    if (gr < M) {
                        float v = acc[i][j][r] + bv;
                        if (ACT == 1) v = fmaxf(v, 0.f);
                        C[(size_t)gr * N + col] = f2b(v);
                    }
                }
            }
        }
    } else {
        unsigned char* C8 = (unsigned char*)Cout;
#pragma unroll
        for (int i = 0; i < 4; i++) {
            int row = gm0 + wrow + i * 16 + quad * 4;
#pragma unroll
            for (int j = 0; j < 4; j++) {
                int col = gn0 + wcol + j * 16 + l15;
#pragma unroll
                for (int r = 0; r < 4; r++) {
                    int gr = row + r;
                    if (gr < M) C8[(size_t)gr * N + col] = f2fp8(acc[i][j][r]);
                }
            }
        }
    }

    if (ALPHA) {
        int hh = blockIdx.x;
        float as_c[4], ad_c[4];
#pragma unroll
        for (int j = 0; j < 4; j++) {
            int c = gn0 + wcol + j * 16 + l15;
            as_c[j] = a_src[c];
            ad_c[j] = a_dst[c];
        }
#pragma unroll
        for (int i = 0; i < 4; i++) {
#pragma unroll
            for (int r = 0; r < 4; r++) {
                float ps = 0.f, pd = 0.f;
#pragma unroll
                for (int j = 0; j < 4; j++) {
                    ps += acc[i][j][r] * as_c[j];
                    pd += acc[i][j][r] * ad_c[j];
                }
#pragma unroll
                for (int o = 1; o < 16; o <<= 1) {
                    ps += __shfl_xor(ps, o);
                    pd += __shfl_xor(pd, o);
                }
                if (wcol == 64 && l15 == 0) {
                    int lr = wrow + i * 16 + quad * 4 + r;
                    sAl[lr][0] = ps;
                    sAl[lr][1] = pd;
                }
            }
        }
        __syncthreads();
        if (wcol == 0) {
#pragma unroll
            for (int i = 0; i < 4; i++) {
#pragma unroll
                for (int r = 0; r < 4; r++) {
                    float ps = 0.f, pd = 0.f;
#pragma unroll
                    for (int j = 0; j < 4; j++) {
                        ps += acc[i][j][r] * as_c[j];
                        pd += acc[i][j][r] * ad_c[j];
                    }
#pragma unroll
                    for (int o = 1; o < 16; o <<= 1) {
                        ps += __shfl_xor(ps, o);
                        pd += __shfl_xor(pd, o);
                    }
                    if (l15 == 0) {
                        int lr = wrow + i * 16 + quad * 4 + r;
                        int gr = gm0 + lr;
                        if (gr < M) {
                            as_out[(size_t)gr * H + hh] = ps + sAl[lr][0];
                            ad_out[(size_t)gr * H + hh] = pd + sAl[lr][1];
                        }
                    }
                }
            }
        }
    }
}

// ---------------- GAT agg L1 (H=4): 1 wave/node, fp8 gather, 4-edge MLP -------
// 4-edge unroll is the measured sweet spot (VGPR 36 / occ 59%); 8-deep regressed.
// r15: packed f32x2 accumulators — cvt_pk_f32_fp8 pairs feed v_pk_fma_f32.
__global__ __launch_bounds__(256) void gat_agg_l1(const unsigned* __restrict__ hq,
                                                  const float4* __restrict__ as4,
                                                  const float4* __restrict__ ad4,
                                                  const int* __restrict__ rowptr,
                                                  const int* __restrict__ esrc,
                                                  const float* __restrict__ bias,
                                                  unsigned short* __restrict__ out, int N) {
    __shared__ float wlds_all[4][256];
    int w = threadIdx.x >> 6, lane = threadIdx.x & 63;
    int n = blockIdx.x * 4 + w;
    if (n >= N) return;
    float* wlds = wlds_all[w];
    int2 rp = *(const int2*)&rowptr[n];    // one 8B load: begin, end
    int begin = rp.x, deg = rp.y - rp.x;
    float4 adn = ad4[n];

    int s_l0 = 0;
    float4 e0 = {-3.4e38f, -3.4e38f, -3.4e38f, -3.4e38f};
    if (lane < deg) {
        s_l0 = esrc[begin + lane];
        float4 u = as4[s_l0];
        e0.x = LRELU(u.x + adn.x); e0.y = LRELU(u.y + adn.y);
        e0.z = LRELU(u.z + adn.z); e0.w = LRELU(u.w + adn.w);
    }
    float4 m = e0;
    for (int base = 64; base < deg; base += 64) {
        int j = base + lane;
        if (j < deg) {
            float4 u = as4[esrc[begin + j]];
            m.x = fmaxf(m.x, LRELU(u.x + adn.x)); m.y = fmaxf(m.y, LRELU(u.y + adn.y));
            m.z = fmaxf(m.z, LRELU(u.z + adn.z)); m.w = fmaxf(m.w, LRELU(u.w + adn.w));
        }
    }
#pragma unroll
    for (int o = 32; o >= 1; o >>= 1) {
        m.x = fmaxf(m.x, __shfl_xor(m.x, o));
        m.y = fmaxf(m.y, __shfl_xor(m.y, o));
        m.z = fmaxf(m.z, __shfl_xor(m.z, o));
        m.w = fmaxf(m.w, __shfl_xor(m.w, o));
    }
    float4 s4 = {0.f, 0.f, 0.f, 0.f};
    if (lane < deg) {
        s4.x = __expf(e0.x - m.x); s4.y = __expf(e0.y - m.y);
        s4.z = __expf(e0.z - m.z); s4.w = __expf(e0.w - m.w);
    }
    for (int base = 64; base < deg; base += 64) {
        int j = base + lane;
        if (j < deg) {
            float4 u = as4[esrc[begin + j]];
            s4.x += __expf(LRELU(u.x + adn.x) - m.x); s4.y += __expf(LRELU(u.y + adn.y) - m.y);
            s4.z += __expf(LRELU(u.z + adn.z) - m.z); s4.w += __expf(LRELU(u.w + adn.w) - m.w);
        }
    }
#pragma unroll
    for (int o = 32; o >= 1; o >>= 1) {
        s4.x += __shfl_xor(s4.x, o); s4.y += __shfl_xor(s4.y, o);
        s4.z += __shfl_xor(s4.z, o); s4.w += __shfl_xor(s4.w, o);
    }
    float4 inv = {1.f / (s4.x + 1e-16f), 1.f / (s4.y + 1e-16f),
                  1.f / (s4.z + 1e-16f), 1.f / (s4.w + 1e-16f)};

    f32x2 acc2[4] = {};
    int h = lane >> 4;
#define ACC_E1(q, wgt) { \
    f32x2 wv = {wgt, wgt}; \
    acc2[0] += wv * __builtin_amdgcn_cvt_pk_f32_fp8((int)q.x, false); \
    acc2[1] += wv * __builtin_amdgcn_cvt_pk_f32_fp8((int)q.x, true);  \
    acc2[2] += wv * __builtin_amdgcn_cvt_pk_f32_fp8((int)q.y, false); \
    acc2[3] += wv * __builtin_amdgcn_cvt_pk_f32_fp8((int)q.y, true);  }

    for (int base = 0; base < deg; base += 64) {
        int j = base + lane;
        int len = min(64, deg - base);
        int s_l = s_l0;
        float4 e = e0;
        if (base > 0 && j < deg) {
            s_l = esrc[begin + j];
            float4 u = as4[s_l];
            e.x = LRELU(u.x + adn.x); e.y = LRELU(u.y + adn.y);
            e.z = LRELU(u.z + adn.z); e.w = LRELU(u.w + adn.w);
        }
        if (j < deg) {
            float4 wv4 = {__expf(e.x - m.x) * inv.x, __expf(e.y - m.y) * inv.y,
                          __expf(e.z - m.z) * inv.z, __expf(e.w - m.w) * inv.w};
            *(float4*)&wlds[lane * 4] = wv4;
        }
        int c = 0;
        for (; c + 4 <= len; c += 4) {
            int s0 = __builtin_amdgcn_readlane(s_l, c);
            int s1 = __builtin_amdgcn_readlane(s_l, c + 1);
            int s2 = __builtin_amdgcn_readlane(s_l, c + 2);
            int s3 = __builtin_amdgcn_readlane(s_l, c + 3);
            uint2 q0 = *((const uint2*)(hq + (size_t)s0 * 128) + lane);
            uint2 q1 = *((const uint2*)(hq + (size_t)s1 * 128) + lane);
            uint2 q2 = *((const uint2*)(hq + (size_t)s2 * 128) + lane);
            uint2 q3 = *((const uint2*)(hq + (size_t)s3 * 128) + lane);
            float w0 = wlds[c * 4 + h];
            float w1 = wlds[c * 4 + 4 + h];
            float w2 = wlds[c * 4 + 8 + h];
            float w3 = wlds[c * 4 + 12 + h];
            ACC_E1(q0, w0); ACC_E1(q1, w1); ACC_E1(q2, w2); ACC_E1(q3, w3);
        }
        for (; c < len; c++) {
            int s0 = __builtin_amdgcn_readlane(s_l, c);
            uint2 q0 = *((const uint2*)(hq + (size_t)s0 * 128) + lane);
            float w0 = wlds[c * 4 + h];
            ACC_E1(q0, w0);
        }
    }
#undef ACC_E1
    int f0 = lane * 8;
    unsigned pk[4];
#pragma unroll
    for (int k = 0; k < 4; k++) {
        float v0 = acc2[k].x + bias[f0 + 2 * k];
        float v1 = acc2[k].y + bias[f0 + 2 * k + 1];
        v0 = v0 > 0.f ? v0 : (__expf(v0) - 1.f);
        v1 = v1 > 0.f ? v1 : (__expf(v1) - 1.f);
        pk[k] = (unsigned)f2b(v0) | ((unsigned)f2b(v1) << 16);
    }
    uint4 pv = {pk[0], pk[1], pk[2], pk[3]};
    *((uint4*)(out + (size_t)n * 512) + lane) = pv;
}

// ---------------- GAT agg L2 (H=1): 1 wave/node, fp8 gather, 4-edge MLP -------
// r15: packed f32x2 accumulator.
__global__ __launch_bounds__(256) void gat_agg_l2(const unsigned char* __restrict__ hq,
                                                  const float* __restrict__ as,
                                                  const float* __restrict__ ad,
                                                  const int* __restrict__ rowptr,
                                                  const int* __restrict__ esrc,
                                                  const float* __restrict__ bias,
                                                  float* __restrict__ out, int N) {
    int w = threadIdx.x >> 6, lane = threadIdx.x & 63;
    int n = blockIdx.x * 4 + w;
    if (n >= N) return;
    int2 rp = *(const int2*)&rowptr[n];
    int begin = rp.x, deg = rp.y - rp.x;
    float adn = ad[n];

    int s_l0 = 0;
    float e0 = -3.4e38f;
    if (lane < deg) {
        s_l0 = esrc[begin + lane];
        e0 = LRELU(as[s_l0] + adn);
    }
    float m = e0;
    for (int base = 64; base < deg; base += 64) {
        int j = base + lane;
        if (j < deg) m = fmaxf(m, LRELU(as[esrc[begin + j]] + adn));
    }
#pragma unroll
    for (int o = 32; o >= 1; o >>= 1) m = fmaxf(m, __shfl_xor(m, o));

    float s = (lane < deg) ? __expf(e0 - m) : 0.f;
    for (int base = 64; base < deg; base += 64) {
        int j = base + lane;
        if (j < deg) s += __expf(LRELU(as[esrc[begin + j]] + adn) - m);
    }
#pragma unroll
    for (int o = 32; o >= 1; o >>= 1) s += __shfl_xor(s, o);
    float inv = 1.f / (s + 1e-16f);

    f32x2 acc2 = {0.f, 0.f};
    for (int base = 0; base < deg; base += 64) {
        int j = base + lane;
        int len = min(64, deg - base);
        int s_l = s_l0;
        float e = e0;
        if (base > 0 && j < deg) {
            s_l = esrc[begin + j];
            e = LRELU(as[s_l] + adn);
        }
        float w_l = (j < deg) ? __expf(e - m) * inv : 0.f;
        int c = 0;
        for (; c + 4 <= len; c += 4) {
            int sp0 = __builtin_amdgcn_readlane(s_l, c);
            int sp1 = __builtin_amdgcn_readlane(s_l, c + 1);
            int sp2 = __builtin_amdgcn_readlane(s_l, c + 2);
            int sp3 = __builtin_amdgcn_readlane(s_l, c + 3);
            unsigned short u0 = *((const unsigned short*)(hq + (size_t)sp0 * 128) + lane);
            unsigned short u1 = *((const unsigned short*)(hq + (size_t)sp1 * 128) + lane);
            unsigned short u2 = *((const unsigned short*)(hq + (size_t)sp2 * 128) + lane);
            unsigned short u3 = *((const unsigned short*)(hq + (size_t)sp3 * 128) + lane);
            float w0 = rl_f(w_l, c), w1 = rl_f(w_l, c + 1);
            float w2 = rl_f(w_l, c + 2), w3 = rl_f(w_l, c + 3);
            f32x2 wv0 = {w0, w0}, wv1 = {w1, w1}, wv2 = {w2, w2}, wv3 = {w3, w3};
            acc2 += wv0 * __builtin_amdgcn_cvt_pk_f32_fp8((int)u0, false);
            acc2 += wv1 * __builtin_amdgcn_cvt_pk_f32_fp8((int)u1, false);
            acc2 += wv2 * __builtin_amdgcn_cvt_pk_f32_fp8((int)u2, false);
            acc2 += wv3 * __builtin_amdgcn_cvt_pk_f32_fp8((int)u3, false);
        }
        for (; c < len; c++) {
            int sp0 = __builtin_amdgcn_readlane(s_l, c);
            float w0 = rl_f(w_l, c);
            unsigned short u0 = *((const unsigned short*)(hq + (size_t)sp0 * 128) + lane);
            f32x2 wv0 = {w0, w0};
            acc2 += wv0 * __builtin_amdgcn_cvt_pk_f32_fp8((int)u0, false);
        }
    }
    float v0 = acc2.x + bias[lane * 2];
    float v1 = acc2.y + bias[lane * 2 + 1];
    v0 = v0 > 0.f ? v0 : (__expf(v0) - 1.f);
    v1 = v1 > 0.f ? v1 : (__expf(v1) - 1.f);
    float2 pv = {v0, v1};
    *(float2*)&out[(size_t)n * 128 + lane * 2] = pv;
}

// ---------------- mean pool + final GEMV (fused via done-counter) -------------
__global__ __launch_bounds__(256) void pool_final_kernel(const float* __restrict__ o2,
                                                         float* __restrict__ pool,
                                                         int* __restrict__ done,
                                                         const float* __restrict__ Wout,
                                                         const float* __restrict__ bout,
                                                         float* __restrict__ out,
                                                         int N, int nblocks, float invN) {
    __shared__ float4 sred[256];
    int f4 = threadIdx.x & 31;
    int r = blockIdx.x * 256 + (threadIdx.x >> 5);
    float4 acc = {0.f, 0.f, 0.f, 0.f};
    for (int i = 0; i < 32; i++, r += 8) {
        if (r < N) {
            float4 v = *(const float4*)&o2[(size_t)r * 128 + f4 * 4];
            acc.x += v.x; acc.y += v.y; acc.z += v.z; acc.w += v.w;
        }
    }
    sred[threadIdx.x] = acc;
    __syncthreads();
    if (threadIdx.x < 32) {
        float4 t = sred[threadIdx.x];
#pragma unroll
        for (int k = 1; k < 8; k++) {
            float4 u = sred[threadIdx.x + 32 * k];
            t.x += u.x; t.y += u.y; t.z += u.z; t.w += u.w;
        }
        atomicAdd(&pool[f4 * 4 + 0], t.x);
        atomicAdd(&pool[f4 * 4 + 1], t.y);
        atomicAdd(&pool[f4 * 4 + 2], t.z);
        atomicAdd(&pool[f4 * 4 + 3], t.w);
    }
    __threadfence();
    __shared__ int isLast;
    if (threadIdx.x == 0) isLast = (atomicAdd(done, 1) == nblocks - 1);
    __syncthreads();
    if (isLast) {
        __shared__ float spool[128];
        if (threadIdx.x < 128) spool[threadIdx.x] = atomicAdd(&pool[threadIdx.x], 0.f);
        __syncthreads();
        int o = threadIdx.x;
        float a = 0.f;
        for (int k = 0; k < 128; k++) a += spool[k] * Wout[k * 256 + o];
        out[o] = a * invN + bout[o];
    }
}

// ---------------- launch ------------------------------------------------------
extern "C" void kernel_launch(void* const* d_in, const int* in_sizes, int n_in,
                              void* d_out, int out_size, void* d_ws, size_t ws_size,
                              hipStream_t stream) {
    const float* x      = (const float*)d_in[0];
    const int*   ei     = (const int*)d_in[1];
    const float* W_emb  = (const float*)d_in[2];
    const float* b_emb  = (const float*)d_in[3];
    const float* W1     = (const float*)d_in[4];
    const float* a1_src = (const float*)d_in[5];
    const float* a1_dst = (const float*)d_in[6];
    const float* b1     = (const float*)d_in[7];
    const float* W2     = (const float*)d_in[8];
    const float* a2_src = (const float*)d_in[9];
    const float* a2_dst = (const float*)d_in[10];
    const float* b2     = (const float*)d_in[11];
    const float* W_out  = (const float*)d_in[12];
    const float* b_out  = (const float*)d_in[13];
    float* out = (float*)d_out;

    const int N = in_sizes[0] / 64;   // 25000
    const int E = in_sizes[1] / 2;    // 400000
    const int Etot = E + N;
    const int nb = (N + 255) / 256;   // 98 blocks — must stay <= CU count (lookback co-residency)
    const int mtiles = (N + 127) / 128;   // 196
    const int nrb = mtiles * 8;           // 16-row fragment blocks incl. tail

    char* ws = (char*)d_ws;
    size_t off = 0;
    auto alloc = [&](size_t bytes) -> void* {
        void* p = ws + off;
        off = (off + bytes + 255) & ~(size_t)255;
        return p;
    };
    typedef unsigned short u16;
    u16* xbS   = (u16*)alloc((size_t)nrb * 1024 * 2);     // frag-swizzled x (bf16)
    u16* WeS   = (u16*)alloc((size_t)8 * 1024 * 2);       // frag-swizzled We
    u16* W1S   = (u16*)alloc((size_t)32 * 2048 * 2);      // frag-swizzled W1
    u16* W2T   = (u16*)alloc((size_t)128 * 512 * 2);
    unsigned char* h1q = (unsigned char*)alloc((size_t)N * 512);   // fp8
    u16* o1b   = (u16*)alloc((size_t)N * 512 * 2);
    unsigned char* h2q = (unsigned char*)alloc((size_t)N * 128);   // fp8
    float* o2  = (float*)alloc((size_t)N * 128 * 4);
    float* as1 = (float*)alloc((size_t)N * 4 * 4);
    float* ad1 = (float*)alloc((size_t)N * 4 * 4);
    float* as2 = (float*)alloc((size_t)N * 4);
    float* ad2 = (float*)alloc((size_t)N * 4);
    float* pool = (float*)alloc(128 * 4);
    int* done   = (int*)alloc(256);
    int* rowptr = (int*)alloc((size_t)(N + 1) * 4);
    int* deg    = (int*)alloc((size_t)N * 4);
    int* cursor = (int*)alloc((size_t)N * 4);
    int* sagg   = (int*)alloc((size_t)nb * 4);
    int* sflg   = (int*)alloc((size_t)nb * 4);
    int* esrc   = (int*)alloc((size_t)Etot * 4);

    const int blocksE = (Etot + 255) / 256;
    const int Nx = N * 64;
    const int prepElems = Nx + 64 * 128 + 128 * 512 + 512 * 128;
    const int prepBlocks = (prepElems + 255) / 256;

    // K1: zero deg/pool/done + scan flags & aggs
    int zn = N + 128 + 1 + 2 * nb;
    zero_kernel<<<(zn + 255) / 256, 256, 0, stream>>>(deg, pool, done, sflg, sagg, N, nb);

    // K2: degree histogram (atomics) ∥ swizzled bf16 conversions
    degcount_prep<<<blocksE + prepBlocks, 256, 0, stream>>>(ei, E, N, deg, blocksE,
                                                            x, W_emb, W1, W2,
                                                            xbS, WeS, W1S, W2T, Nx);

    // K3: single-dispatch exclusive scan (decoupled lookback) + cursor seed
    scan_lookback<<<nb, 256, 0, stream>>>(deg, rowptr, cursor, sagg, sflg, N, nb);

    // K4: CSR scatter (tiny, full occupancy)
    scatter_kernel<<<blocksE, 256, 0, stream>>>(ei, E, N, cursor, esrc);

    // K5: fused GEMM1+2 (h1pre = relu(x@We+be)@W1, fp8 + alpha1), 2-col-split
    gemm12_fused<<<dim3(2, mtiles), 256, 0, stream>>>(xbS, WeS, b_emb, W1S, h1q,
                                                      a1_src, a1_dst, as1, ad1, N);

    // K6: layer-1 aggregation (logits on the fly, fp8 gather)
    gat_agg_l1<<<(N + 3) / 4, 256, 0, stream>>>((const unsigned*)h1q, (const float4*)as1,
                                                (const float4*)ad1, rowptr, esrc, b1, o1b, N);

    // K7: h2pre = o1 @ W2  [N,128] fp8 + fused alpha2 (r19: reg double-buffer)
    gemm_mfma_nt<0, 1, 1, 1><<<dim3(1, mtiles), 256, 0, stream>>>(
        o1b, W2T, nullptr, h2q, a2_src, a2_dst, as2, ad2, N, 128, 512);

    // K8: layer-2 aggregation
    gat_agg_l2<<<(N + 3) / 4, 256, 0, stream>>>(h2q, as2, ad2, rowptr, esrc, b2, o2, N);

    // K9: mean pool + final GEMV
    int npb = (N + 255) / 256;
    pool_final_kernel<<<npb, 256, 0, stream>>>(o2, pool, done, W_out, b_out, out,
                                               N, npb, 1.f / (float)N);
}

// Round 13
// 262.535 us; speedup vs baseline: 1.0449x; 1.0223x over previous
//
#include <hip/hip_runtime.h>
#include <hip/hip_bf16.h>

// N=25000, E=400000 (+N self loops), F_IN=64, HID=128, HEADS=4, OUT=256
// bf16 MFMA GEMMs (embed GEMM fused into layer-1 GEMM via LDS round-trip);
// node-feature gather operands stored fp8(e4m3); alpha dots fused into GEMM
// epilogues (f32-exact); edge logits computed on the fly in agg kernels.
// TUNING LOG (measured):
//  - grid.sync ~30us/barrier on gfx950 — never fuse cheap kernels with it (r5).
//  - agg gather unroll: 4-deep = VGPR 36 / occ 59% / best; 8-deep REGRESSION (r9).
//  - Harness ws-poison fill (~44us, 268MB) is a fixed floor in the trace.
//  - Noise: per-kernel +-3us, total +-4us; BUT r18 vs r20 showed same gemm12
//    code at <43 vs 55-61 — cross-session variance can exceed 25%. Only
//    within-run top-5 rankings are trustworthy.
//  - r10: degcount∥prep + lookback scan + cursor-seed GOOD; scatter∥gemm12
//    fusion BAD (scatter blocks inherited 45KB LDS).
//  - r11/r12: unfuse scatter GOOD. Direct-fragment loads REGRESS if they sit
//    after a barrier (serial L2 chain).
//  - r13/r14 WIN: register-hoist W1 fragment loads above the barrier.
//    gemm12 48-54 -> <44 at dim3(4,196)=784 blocks. Total 265.4 (best).
//  - r15 NEUTRAL: packed f32x2 agg accumulators. Keep.
//  - r16 REGRESSION: rewrote unmeasured gemm_mfma_nt. Reverted.
//  - r17 REGRESSION (measured r20): gemm12 2-col-split dropped grid 784->392
//    (~1.5 blk/CU) -> 55-61us, Occ 14.5. RULE: work-reduction that costs TLP
//    is a net loss in this latency-dominated regime. REVERTED r21.
//  - r19: gemm_mfma_nt register double-buffer (next-tile loads issued after
//    head barrier, overlap MFMA). Stayed below top-5 in r20 bench. Keep.
//  - r21: gemm12 reverted to exact r13 structure (784 blocks, 128-col block,
//    16 W1 frags hoisted pre-barrier).
//  - r22 (this round): identical resubmit of r21 — GPUAcquisitionTimeout
//    (broker capacity). Kernel never executed; no data, no changes.

#define LRELU(x) ((x) > 0.f ? (x) : 0.2f * (x))

typedef short bf16x8 __attribute__((ext_vector_type(8)));
typedef float f32x4 __attribute__((ext_vector_type(4)));
typedef float f32x2 __attribute__((ext_vector_type(2)));

static __device__ __forceinline__ unsigned short f2b(float f) {
    union { float f; unsigned u; } x; x.f = f;
    unsigned r = x.u + 0x7fff + ((x.u >> 16) & 1);
    return (unsigned short)(r >> 16);
}
static __device__ __forceinline__ float rl_f(float v, int c) {
    return __int_as_float(__builtin_amdgcn_readlane(__float_as_int(v), c));
}
static __device__ __forceinline__ unsigned char f2fp8(float v) {
    int p = __builtin_amdgcn_cvt_pk_fp8_f32(v, v, 0, false);
    return (unsigned char)(p & 0xff);
}

// ---------------- zero scratch (deg + pool + done + scan flags/aggs) ----------
__global__ void zero_kernel(int* __restrict__ deg, float* __restrict__ pool,
                            int* __restrict__ done, int* __restrict__ flg,
                            int* __restrict__ agg, int N, int nb) {
    int i = blockIdx.x * blockDim.x + threadIdx.x;
    if (i < N) { deg[i] = 0; return; }
    i -= N;
    if (i < 128) { pool[i] = 0.f; return; }
    i -= 128;
    if (i == 0) { *done = 0; return; }
    i -= 1;
    if (i < nb) { flg[i] = 0; return; }
    i -= nb;
    if (i < nb) agg[i] = 0;
}

// ---------------- fused: degree count (atomics) ∥ prep conversions ------------
// prep writes MFMA-fragment-swizzled bf16 layouts so the GEMM loads fragments
// directly from global (coalesced 1KiB per wave-fragment):
//   xbS idx(r,k)  = (r>>4)*1024 + (k>>3)*128 + (r&15)*8 + (k&7)      [r<25000,k<64]
//   WeS idx(n,k)  = (n>>4)*1024 + (k>>5)*512 + ((k>>3)&3)*128 + (n&15)*8 + (k&7)
//   W1S idx(n,k)  = (n>>4)*2048 + (k>>5)*512 + ((k>>3)&3)*128 + (n&15)*8 + (k&7)
__global__ void degcount_prep(const int* __restrict__ ei, int E, int N,
                              int* __restrict__ deg, int blocksE,
                              const float* __restrict__ x, const float* __restrict__ We,
                              const float* __restrict__ W1, const float* __restrict__ W2,
                              unsigned short* __restrict__ xbS, unsigned short* __restrict__ WeS,
                              unsigned short* __restrict__ W1S, unsigned short* __restrict__ W2T,
                              int Nx) {
    if ((int)blockIdx.x < blocksE) {
        int i = blockIdx.x * blockDim.x + threadIdx.x;
        if (i < E) atomicAdd(&deg[ei[E + i]], 1);
        else if (i < E + N) atomicAdd(&deg[i - E], 1);
        return;
    }
    int i = (blockIdx.x - blocksE) * blockDim.x + threadIdx.x;
    if (i < Nx) {
        int r = i >> 6, k = i & 63;
        xbS[(r >> 4) * 1024 + (k >> 3) * 128 + (r & 15) * 8 + (k & 7)] = f2b(x[i]);
        return;
    }
    i -= Nx;
    if (i < 64 * 128) {
        int k = i >> 7, n = i & 127;
        WeS[(n >> 4) * 1024 + (k >> 5) * 512 + ((k >> 3) & 3) * 128 + (n & 15) * 8 + (k & 7)] = f2b(We[i]);
        return;
    }
    i -= 64 * 128;
    if (i < 128 * 512) {
        int k = i >> 9, n = i & 511;
        W1S[(n >> 4) * 2048 + (k >> 5) * 512 + ((k >> 3) & 3) * 128 + (n & 15) * 8 + (k & 7)] = f2b(W1[i]);
        return;
    }
    i -= 128 * 512;
    if (i < 512 * 128) { int k = i >> 7, n = i & 127; W2T[n * 512 + k] = f2b(W2[i]); return; }
}

// ---------------- single-dispatch exclusive scan (decoupled lookback) ---------
// nb = 98 blocks <= 256 CUs -> all blocks co-resident, spin cannot deadlock.
// Agent-scope release/acquire handles cross-XCD L2 non-coherence. Seeds
// cursor[i] = rowptr[i] so scatter needs only atomicAdd(&cursor[d],1).
__global__ __launch_bounds__(256) void scan_lookback(const int* __restrict__ deg,
                                                     int* __restrict__ rowptr,
                                                     int* __restrict__ cursor,
                                                     int* __restrict__ agg,
                                                     int* __restrict__ flg,
                                                     int N, int nb) {
    __shared__ int sd[256];
    __shared__ int soff;
    int t = threadIdx.x, b = blockIdx.x;
    int i = b * 256 + t;
    int d = (i < N) ? deg[i] : 0;
    sd[t] = d;
    __syncthreads();
    for (int off = 1; off < 256; off <<= 1) {
        int v = (t >= off) ? sd[t - off] : 0;
        __syncthreads();
        sd[t] += v;
        __syncthreads();
    }
    int incl = sd[t];
    int btot = sd[255];
    if (t == 0) {
        soff = 0;
        __hip_atomic_store(&agg[b], btot, __ATOMIC_RELAXED, __HIP_MEMORY_SCOPE_AGENT);
        __hip_atomic_store(&flg[b], 1, __ATOMIC_RELEASE, __HIP_MEMORY_SCOPE_AGENT);
    }
    if (b > 0 && t < 64) {
        int acc = 0;
        for (int p = t; p < b; p += 64) {
            while (__hip_atomic_load(&flg[p], __ATOMIC_ACQUIRE, __HIP_MEMORY_SCOPE_AGENT) == 0)
                __builtin_amdgcn_s_sleep(1);
            acc += __hip_atomic_load(&agg[p], __ATOMIC_RELAXED, __HIP_MEMORY_SCOPE_AGENT);
        }
#pragma unroll
        for (int o = 32; o >= 1; o >>= 1) acc += __shfl_xor(acc, o);
        if (t == 0) soff = acc;
    }
    __syncthreads();
    int off = soff;
    int excl = off + incl - d;
    if (i < N) { rowptr[i] = excl; cursor[i] = excl; }
    if (b == nb - 1 && t == 255) rowptr[N] = off + btot;
}

// ---------------- CSR scatter (tiny, zero LDS, full occupancy) ----------------
__global__ void scatter_kernel(const int* __restrict__ ei, int E, int N,
                               int* __restrict__ cursor, int* __restrict__ esrc) {
    int i = blockIdx.x * blockDim.x + threadIdx.x;
    int s, d;
    if (i < E) { s = ei[i]; d = ei[E + i]; }
    else if (i < E + N) { s = i - E; d = s; }
    else return;
    int pos = atomicAdd(&cursor[d], 1);
    esrc[pos] = s;
}

// ---------------- fused GEMM1+2: h1 = relu(x@We+be)@W1, fp8 out + alpha -------
// r13 structure: dim3(4,196)=784 blocks (~3/CU TLP). Direct fragment loads;
// all 16 phase-2 W1 fragments loaded into registers BEFORE the h0 epilogue +
// barrier (latency hides under epilogue/barrier/LDS reads). Phase 2 has zero
// global loads. __launch_bounds__(256,3) pins regalloc.
__global__ __launch_bounds__(256, 3) void gemm12_fused(const unsigned short* __restrict__ xbS,
                                                       const unsigned short* __restrict__ WeS,
                                                       const float* __restrict__ b_emb,
                                                       const unsigned short* __restrict__ W1S,
                                                       unsigned char* __restrict__ C8,  // [M,512] fp8
                                                       const float* __restrict__ a_src,
                                                       const float* __restrict__ a_dst,
                                                       float* __restrict__ as_out,
                                                       float* __restrict__ ad_out, int M) {
    __shared__ __align__(16) unsigned short h0s[128 * 132];
    __shared__ float sAl[128][2];

    int tid = threadIdx.x;
    int bx = blockIdx.x, by = blockIdx.y;
    int gm0 = by * 128, gn0 = bx * 128;
    int w = tid >> 6, lane = tid & 63;
    int wrow = (w >> 1) * 64, wc = w & 1, wcol = wc * 64;
    int l15 = lane & 15, quad = lane >> 4;

    f32x4 acc[4][4];
#pragma unroll
    for (int i = 0; i < 4; i++)
#pragma unroll
        for (int j = 0; j < 4; j++) acc[i][j] = {0.f, 0.f, 0.f, 0.f};

    // ---- phase 1: emb GEMM (K=64), direct fragment loads ----
    const unsigned short* xA = xbS + (size_t)((gm0 + wrow) >> 4) * 1024 + quad * 128 + l15 * 8;
    const unsigned short* wB = WeS + (size_t)(wc * 4) * 1024 + quad * 128 + l15 * 8;
    const unsigned short* w1B = W1S + (size_t)(bx * 8 + wc * 4) * 2048 + quad * 128 + l15 * 8;
#pragma unroll
    for (int ks = 0; ks < 2; ks++) {
        bf16x8 af[4], bfr[4];
#pragma unroll
        for (int i = 0; i < 4; i++) af[i] = *(const bf16x8*)(xA + i * 1024 + ks * 512);
#pragma unroll
        for (int j = 0; j < 4; j++) bfr[j] = *(const bf16x8*)(wB + j * 1024 + ks * 512);
#pragma unroll
        for (int i = 0; i < 4; i++)
#pragma unroll
            for (int j = 0; j < 4; j++)
                acc[i][j] = __builtin_amdgcn_mfma_f32_16x16x32_bf16(af[i], bfr[j], acc[i][j], 0, 0, 0);
    }

    // ---- issue ALL phase-2 W1 fragment loads now (latency hides under the
    //      h0 epilogue + barrier + phase-2 LDS reads) ----
    bf16x8 wp[4][4];
#pragma unroll
    for (int ks = 0; ks < 4; ks++)
#pragma unroll
        for (int j = 0; j < 4; j++)
            wp[ks][j] = *(const bf16x8*)(w1B + j * 2048 + ks * 512);

    // ---- h0 = relu(acc + be) -> LDS (bf16), single barrier ----
#pragma unroll
    for (int j = 0; j < 4; j++) {
        int col = wcol + j * 16 + l15;
        float bv = b_emb[col];
#pragma unroll
        for (int i = 0; i < 4; i++) {
            int row = wrow + i * 16 + quad * 4;
#pragma unroll
            for (int r = 0; r < 4; r++) {
                float v = fmaxf(acc[i][j][r] + bv, 0.f);
                h0s[(row + r) * 132 + col] = f2b(v);
            }
        }
    }
#pragma unroll
    for (int i = 0; i < 4; i++)
#pragma unroll
        for (int j = 0; j < 4; j++) acc[i][j] = {0.f, 0.f, 0.f, 0.f};
    __syncthreads();

    // ---- phase 2: h0 @ W1 (K=128), A from LDS, B from registers ----
#pragma unroll
    for (int ks = 0; ks < 4; ks++) {
        bf16x8 af[4];
#pragma unroll
        for (int i = 0; i < 4; i++)
            af[i] = *(const bf16x8*)&h0s[(wrow + i * 16 + l15) * 132 + ks * 32 + quad * 8];
#pragma unroll
        for (int i = 0; i < 4; i++)
#pragma unroll
            for (int j = 0; j < 4; j++)
                acc[i][j] = __builtin_amdgcn_mfma_f32_16x16x32_bf16(af[i], wp[ks][j], acc[i][j], 0, 0, 0);
    }

    // ---- C8 = fp8(h1pre) ----
#pragma unroll
    for (int i = 0; i < 4; i++) {
        int row = gm0 + wrow + i * 16 + quad * 4;
#pragma unroll
        for (int j = 0; j < 4; j++) {
            int col = gn0 + wcol + j * 16 + l15;
#pragma unroll
            for (int r = 0; r < 4; r++) {
                int gr = row + r;
                if (gr < M) C8[(size_t)gr * 512 + col] = f2fp8(acc[i][j][r]);
            }
        }
    }

    // ---- fused alpha dots (f32-exact) ----
    {
        int hh = bx;
        float as_c[4], ad_c[4];
#pragma unroll
        for (int j = 0; j < 4; j++) {
            int c = gn0 + wcol + j * 16 + l15;
            as_c[j] = a_src[c];
            ad_c[j] = a_dst[c];
        }
#pragma unroll
        for (int i = 0; i < 4; i++) {
#pragma unroll
            for (int r = 0; r < 4; r++) {
                float ps = 0.f, pd = 0.f;
#pragma unroll
                for (int j = 0; j < 4; j++) {
                    ps += acc[i][j][r] * as_c[j];
                    pd += acc[i][j][r] * ad_c[j];
                }
#pragma unroll
                for (int o = 1; o < 16; o <<= 1) {
                    ps += __shfl_xor(ps, o);
                    pd += __shfl_xor(pd, o);
                }
                if (wcol == 64 && l15 == 0) {
                    int lr = wrow + i * 16 + quad * 4 + r;
                    sAl[lr][0] = ps;
                    sAl[lr][1] = pd;
                }
            }
        }
        __syncthreads();
        if (wcol == 0) {
#pragma unroll
            for (int i = 0; i < 4; i++) {
#pragma unroll
                for (int r = 0; r < 4; r++) {
                    float ps = 0.f, pd = 0.f;
#pragma unroll
                    for (int j = 0; j < 4; j++) {
                        ps += acc[i][j][r] * as_c[j];
                        pd += acc[i][j][r] * ad_c[j];
                    }
#pragma unroll
                    for (int o = 1; o < 16; o <<= 1) {
                        ps += __shfl_xor(ps, o);
                        pd += __shfl_xor(pd, o);
                    }
                    if (l15 == 0) {
                        int lr = wrow + i * 16 + quad * 4 + r;
                        int gr = gm0 + lr;
                        if (gr < M) {
                            as_out[(size_t)gr * 4 + hh] = ps + sAl[lr][0];
                            ad_out[(size_t)gr * 4 + hh] = pd + sAl[lr][1];
                        }
                    }
                }
            }
        }
    }
}

// ---------------- MFMA bf16 NT GEMM (layer 2): fp8 out + fused alpha ----------
// r19: register double-buffer. Tile k0+32's global loads are issued right
// after the head barrier of step k0, overlapping ds_read+MFMA+tail barrier.
template <int ACT, int OFMT, int ALPHA, int H>
__global__ __launch_bounds__(256) void gemm_mfma_nt(const unsigned short* __restrict__ A,
                                                    const unsigned short* __restrict__ Bt,
                                                    const float* __restrict__ bias,
                                                    void* __restrict__ Cout,
                                                    const float* __restrict__ a_src,
                                                    const float* __restrict__ a_dst,
                                                    float* __restrict__ as_out,
                                                    float* __restrict__ ad_out,
                                                    int M, int N, int K) {
    __shared__ __align__(16) unsigned short As[128 * 40];
    __shared__ __align__(16) unsigned short Bs[128 * 40];
    __shared__ float sAl[128][2];
    int tid = threadIdx.x;
    int gm0 = blockIdx.y * 128, gn0 = blockIdx.x * 128;
    int w = tid >> 6, lane = tid & 63;
    int wrow = (w >> 1) * 64, wcol = (w & 1) * 64;
    int l15 = lane & 15, quad = lane >> 4;

    f32x4 acc[4][4];
#pragma unroll
    for (int i = 0; i < 4; i++)
#pragma unroll
        for (int j = 0; j < 4; j++) acc[i][j] = {0.f, 0.f, 0.f, 0.f};

    // per-thread staging addresses (constant across K-steps except k0)
    int lin0 = tid, lin1 = tid + 256;
    int row0 = lin0 >> 2, cg0 = (lin0 & 3) * 8;
    int row1 = lin1 >> 2, cg1 = (lin1 & 3) * 8;
    int ga0 = gm0 + row0; if (ga0 >= M) ga0 = M - 1;
    int ga1 = gm0 + row1; if (ga1 >= M) ga1 = M - 1;
    const unsigned short* pa0 = A + (size_t)ga0 * K + cg0;
    const unsigned short* pa1 = A + (size_t)ga1 * K + cg1;
    const unsigned short* pb0 = Bt + (size_t)(gn0 + row0) * K + cg0;
    const unsigned short* pb1 = Bt + (size_t)(gn0 + row1) * K + cg1;

    // prologue: load tile k0=0
    uint4 va0 = *(const uint4*)(pa0);
    uint4 va1 = *(const uint4*)(pa1);
    uint4 vb0 = *(const uint4*)(pb0);
    uint4 vb1 = *(const uint4*)(pb1);

    for (int k0 = 0; k0 < K; k0 += 32) {
        *(uint4*)&As[row0 * 40 + cg0] = va0;
        *(uint4*)&As[row1 * 40 + cg1] = va1;
        *(uint4*)&Bs[row0 * 40 + cg0] = vb0;
        *(uint4*)&Bs[row1 * 40 + cg1] = vb1;
        __syncthreads();
        if (k0 + 32 < K) {       // issue NEXT tile loads; overlap MFMA below
            va0 = *(const uint4*)(pa0 + k0 + 32);
            va1 = *(const uint4*)(pa1 + k0 + 32);
            vb0 = *(const uint4*)(pb0 + k0 + 32);
            vb1 = *(const uint4*)(pb1 + k0 + 32);
        }
        bf16x8 af[4], bfr[4];
#pragma unroll
        for (int i = 0; i < 4; i++) {
            af[i]  = *(const bf16x8*)&As[(wrow + i * 16 + l15) * 40 + quad * 8];
            bfr[i] = *(const bf16x8*)&Bs[(wcol + i * 16 + l15) * 40 + quad * 8];
        }
#pragma unroll
        for (int i = 0; i < 4; i++)
#pragma unroll
            for (int j = 0; j < 4; j++)
                acc[i][j] = __builtin_amdgcn_mfma_f32_16x16x32_bf16(af[i], bfr[j], acc[i][j], 0, 0, 0);
        __syncthreads();
    }

    if (OFMT == 0) {
        unsigned short* C = (unsigned short*)Cout;
#pragma unroll
        for (int i = 0; i < 4; i++) {
            int row = gm0 + wrow + i * 16 + quad * 4;
#pragma unroll
            for (int j = 0; j < 4; j++) {
                int col = gn0 + wcol + j * 16 + l15;
                float bv = bias ? bias[col] : 0.f;
#pragma unroll
                for (int r = 0; r < 4; r++) {
                    int gr = row + r;
                    if (gr < M) {
                        float v = acc[i][j][r] + bv;
                        if (ACT == 1) v = fmaxf(v, 0.f);
                        C[(size_t)gr * N + col] = f2b(v);
                    }
                }
            }
        }
    } else {
        unsigned char* C8 = (unsigned char*)Cout;
#pragma unroll
        for (int i = 0; i < 4; i++) {
            int row = gm0 + wrow + i * 16 + quad * 4;
#pragma unroll
            for (int j = 0; j < 4; j++) {
                int col = gn0 + wcol + j * 16 + l15;
#pragma unroll
                for (int r = 0; r < 4; r++) {
                    int gr = row + r;
                    if (gr < M) C8[(size_t)gr * N + col] = f2fp8(acc[i][j][r]);
                }
            }
        }
    }

    if (ALPHA) {
        int hh = blockIdx.x;
        float as_c[4], ad_c[4];
#pragma unroll
        for (int j = 0; j < 4; j++) {
            int c = gn0 + wcol + j * 16 + l15;
            as_c[j] = a_src[c];
            ad_c[j] = a_dst[c];
        }
#pragma unroll
        for (int i = 0; i < 4; i++) {
#pragma unroll
            for (int r = 0; r < 4; r++) {
                float ps = 0.f, pd = 0.f;
#pragma unroll
                for (int j = 0; j < 4; j++) {
                    ps += acc[i][j][r] * as_c[j];
                    pd += acc[i][j][r] * ad_c[j];
                }
#pragma unroll
                for (int o = 1; o < 16; o <<= 1) {
                    ps += __shfl_xor(ps, o);
                    pd += __shfl_xor(pd, o);
                }
                if (wcol == 64 && l15 == 0) {
                    int lr = wrow + i * 16 + quad * 4 + r;
                    sAl[lr][0] = ps;
                    sAl[lr][1] = pd;
                }
            }
        }
        __syncthreads();
        if (wcol == 0) {
#pragma unroll
            for (int i = 0; i < 4; i++) {
#pragma unroll
                for (int r = 0; r < 4; r++) {
                    float ps = 0.f, pd = 0.f;
#pragma unroll
                    for (int j = 0; j < 4; j++) {
                        ps += acc[i][j][r] * as_c[j];
                        pd += acc[i][j][r] * ad_c[j];
                    }
#pragma unroll
                    for (int o = 1; o < 16; o <<= 1) {
                        ps += __shfl_xor(ps, o);
                        pd += __shfl_xor(pd, o);
                    }
                    if (l15 == 0) {
                        int lr = wrow + i * 16 + quad * 4 + r;
                        int gr = gm0 + lr;
                        if (gr < M) {
                            as_out[(size_t)gr * H + hh] = ps + sAl[lr][0];
                            ad_out[(size_t)gr * H + hh] = pd + sAl[lr][1];
                        }
                    }
                }
            }
        }
    }
}

// ---------------- GAT agg L1 (H=4): 1 wave/node, fp8 gather, 4-edge MLP -------
// 4-edge unroll is the measured sweet spot (VGPR 36 / occ 59%); 8-deep regressed.
// r15: packed f32x2 accumulators — cvt_pk_f32_fp8 pairs feed v_pk_fma_f32.
__global__ __launch_bounds__(256) void gat_agg_l1(const unsigned* __restrict__ hq,
                                                  const float4* __restrict__ as4,
                                                  const float4* __restrict__ ad4,
                                                  const int* __restrict__ rowptr,
                                                  const int* __restrict__ esrc,
                                                  const float* __restrict__ bias,
                                                  unsigned short* __restrict__ out, int N) {
    __shared__ float wlds_all[4][256];
    int w = threadIdx.x >> 6, lane = threadIdx.x & 63;
    int n = blockIdx.x * 4 + w;
    if (n >= N) return;
    float* wlds = wlds_all[w];
    int2 rp = *(const int2*)&rowptr[n];    // one 8B load: begin, end
    int begin = rp.x, deg = rp.y - rp.x;
    float4 adn = ad4[n];

    int s_l0 = 0;
    float4 e0 = {-3.4e38f, -3.4e38f, -3.4e38f, -3.4e38f};
    if (lane < deg) {
        s_l0 = esrc[begin + lane];
        float4 u = as4[s_l0];
        e0.x = LRELU(u.x + adn.x); e0.y = LRELU(u.y + adn.y);
        e0.z = LRELU(u.z + adn.z); e0.w = LRELU(u.w + adn.w);
    }
    float4 m = e0;
    for (int base = 64; base < deg; base += 64) {
        int j = base + lane;
        if (j < deg) {
            float4 u = as4[esrc[begin + j]];
            m.x = fmaxf(m.x, LRELU(u.x + adn.x)); m.y = fmaxf(m.y, LRELU(u.y + adn.y));
            m.z = fmaxf(m.z, LRELU(u.z + adn.z)); m.w = fmaxf(m.w, LRELU(u.w + adn.w));
        }
    }
#pragma unroll
    for (int o = 32; o >= 1; o >>= 1) {
        m.x = fmaxf(m.x, __shfl_xor(m.x, o));
        m.y = fmaxf(m.y, __shfl_xor(m.y, o));
        m.z = fmaxf(m.z, __shfl_xor(m.z, o));
        m.w = fmaxf(m.w, __shfl_xor(m.w, o));
    }
    float4 s4 = {0.f, 0.f, 0.f, 0.f};
    if (lane < deg) {
        s4.x = __expf(e0.x - m.x); s4.y = __expf(e0.y - m.y);
        s4.z = __expf(e0.z - m.z); s4.w = __expf(e0.w - m.w);
    }
    for (int base = 64; base < deg; base += 64) {
        int j = base + lane;
        if (j < deg) {
            float4 u = as4[esrc[begin + j]];
            s4.x += __expf(LRELU(u.x + adn.x) - m.x); s4.y += __expf(LRELU(u.y + adn.y) - m.y);
            s4.z += __expf(LRELU(u.z + adn.z) - m.z); s4.w += __expf(LRELU(u.w + adn.w) - m.w);
        }
    }
#pragma unroll
    for (int o = 32; o >= 1; o >>= 1) {
        s4.x += __shfl_xor(s4.x, o); s4.y += __shfl_xor(s4.y, o);
        s4.z += __shfl_xor(s4.z, o); s4.w += __shfl_xor(s4.w, o);
    }
    float4 inv = {1.f / (s4.x + 1e-16f), 1.f / (s4.y + 1e-16f),
                  1.f / (s4.z + 1e-16f), 1.f / (s4.w + 1e-16f)};

    f32x2 acc2[4] = {};
    int h = lane >> 4;
#define ACC_E1(q, wgt) { \
    f32x2 wv = {wgt, wgt}; \
    acc2[0] += wv * __builtin_amdgcn_cvt_pk_f32_fp8((int)q.x, false); \
    acc2[1] += wv * __builtin_amdgcn_cvt_pk_f32_fp8((int)q.x, true);  \
    acc2[2] += wv * __builtin_amdgcn_cvt_pk_f32_fp8((int)q.y, false); \
    acc2[3] += wv * __builtin_amdgcn_cvt_pk_f32_fp8((int)q.y, true);  }

    for (int base = 0; base < deg; base += 64) {
        int j = base + lane;
        int len = min(64, deg - base);
        int s_l = s_l0;
        float4 e = e0;
        if (base > 0 && j < deg) {
            s_l = esrc[begin + j];
            float4 u = as4[s_l];
            e.x = LRELU(u.x + adn.x); e.y = LRELU(u.y + adn.y);
            e.z = LRELU(u.z + adn.z); e.w = LRELU(u.w + adn.w);
        }
        if (j < deg) {
            float4 wv4 = {__expf(e.x - m.x) * inv.x, __expf(e.y - m.y) * inv.y,
                          __expf(e.z - m.z) * inv.z, __expf(e.w - m.w) * inv.w};
            *(float4*)&wlds[lane * 4] = wv4;
        }
        int c = 0;
        for (; c + 4 <= len; c += 4) {
            int s0 = __builtin_amdgcn_readlane(s_l, c);
            int s1 = __builtin_amdgcn_readlane(s_l, c + 1);
            int s2 = __builtin_amdgcn_readlane(s_l, c + 2);
            int s3 = __builtin_amdgcn_readlane(s_l, c + 3);
            uint2 q0 = *((const uint2*)(hq + (size_t)s0 * 128) + lane);
            uint2 q1 = *((const uint2*)(hq + (size_t)s1 * 128) + lane);
            uint2 q2 = *((const uint2*)(hq + (size_t)s2 * 128) + lane);
            uint2 q3 = *((const uint2*)(hq + (size_t)s3 * 128) + lane);
            float w0 = wlds[c * 4 + h];
            float w1 = wlds[c * 4 + 4 + h];
            float w2 = wlds[c * 4 + 8 + h];
            float w3 = wlds[c * 4 + 12 + h];
            ACC_E1(q0, w0); ACC_E1(q1, w1); ACC_E1(q2, w2); ACC_E1(q3, w3);
        }
        for (; c < len; c++) {
            int s0 = __builtin_amdgcn_readlane(s_l, c);
            uint2 q0 = *((const uint2*)(hq + (size_t)s0 * 128) + lane);
            float w0 = wlds[c * 4 + h];
            ACC_E1(q0, w0);
        }
    }
#undef ACC_E1
    int f0 = lane * 8;
    unsigned pk[4];
#pragma unroll
    for (int k = 0; k < 4; k++) {
        float v0 = acc2[k].x + bias[f0 + 2 * k];
        float v1 = acc2[k].y + bias[f0 + 2 * k + 1];
        v0 = v0 > 0.f ? v0 : (__expf(v0) - 1.f);
        v1 = v1 > 0.f ? v1 : (__expf(v1) - 1.f);
        pk[k] = (unsigned)f2b(v0) | ((unsigned)f2b(v1) << 16);
    }
    uint4 pv = {pk[0], pk[1], pk[2], pk[3]};
    *((uint4*)(out + (size_t)n * 512) + lane) = pv;
}

// ---------------- GAT agg L2 (H=1): 1 wave/node, fp8 gather, 4-edge MLP -------
// r15: packed f32x2 accumulator.
__global__ __launch_bounds__(256) void gat_agg_l2(const unsigned char* __restrict__ hq,
                                                  const float* __restrict__ as,
                                                  const float* __restrict__ ad,
                                                  const int* __restrict__ rowptr,
                                                  const int* __restrict__ esrc,
                                                  const float* __restrict__ bias,
                                                  float* __restrict__ out, int N) {
    int w = threadIdx.x >> 6, lane = threadIdx.x & 63;
    int n = blockIdx.x * 4 + w;
    if (n >= N) return;
    int2 rp = *(const int2*)&rowptr[n];
    int begin = rp.x, deg = rp.y - rp.x;
    float adn = ad[n];

    int s_l0 = 0;
    float e0 = -3.4e38f;
    if (lane < deg) {
        s_l0 = esrc[begin + lane];
        e0 = LRELU(as[s_l0] + adn);
    }
    float m = e0;
    for (int base = 64; base < deg; base += 64) {
        int j = base + lane;
        if (j < deg) m = fmaxf(m, LRELU(as[esrc[begin + j]] + adn));
    }
#pragma unroll
    for (int o = 32; o >= 1; o >>= 1) m = fmaxf(m, __shfl_xor(m, o));

    float s = (lane < deg) ? __expf(e0 - m) : 0.f;
    for (int base = 64; base < deg; base += 64) {
        int j = base + lane;
        if (j < deg) s += __expf(LRELU(as[esrc[begin + j]] + adn) - m);
    }
#pragma unroll
    for (int o = 32; o >= 1; o >>= 1) s += __shfl_xor(s, o);
    float inv = 1.f / (s + 1e-16f);

    f32x2 acc2 = {0.f, 0.f};
    for (int base = 0; base < deg; base += 64) {
        int j = base + lane;
        int len = min(64, deg - base);
        int s_l = s_l0;
        float e = e0;
        if (base > 0 && j < deg) {
            s_l = esrc[begin + j];
            e = LRELU(as[s_l] + adn);
        }
        float w_l = (j < deg) ? __expf(e - m) * inv : 0.f;
        int c = 0;
        for (; c + 4 <= len; c += 4) {
            int sp0 = __builtin_amdgcn_readlane(s_l, c);
            int sp1 = __builtin_amdgcn_readlane(s_l, c + 1);
            int sp2 = __builtin_amdgcn_readlane(s_l, c + 2);
            int sp3 = __builtin_amdgcn_readlane(s_l, c + 3);
            unsigned short u0 = *((const unsigned short*)(hq + (size_t)sp0 * 128) + lane);
            unsigned short u1 = *((const unsigned short*)(hq + (size_t)sp1 * 128) + lane);
            unsigned short u2 = *((const unsigned short*)(hq + (size_t)sp2 * 128) + lane);
            unsigned short u3 = *((const unsigned short*)(hq + (size_t)sp3 * 128) + lane);
            float w0 = rl_f(w_l, c), w1 = rl_f(w_l, c + 1);
            float w2 = rl_f(w_l, c + 2), w3 = rl_f(w_l, c + 3);
            f32x2 wv0 = {w0, w0}, wv1 = {w1, w1}, wv2 = {w2, w2}, wv3 = {w3, w3};
            acc2 += wv0 * __builtin_amdgcn_cvt_pk_f32_fp8((int)u0, false);
            acc2 += wv1 * __builtin_amdgcn_cvt_pk_f32_fp8((int)u1, false);
            acc2 += wv2 * __builtin_amdgcn_cvt_pk_f32_fp8((int)u2, false);
            acc2 += wv3 * __builtin_amdgcn_cvt_pk_f32_fp8((int)u3, false);
        }
        for (; c < len; c++) {
            int sp0 = __builtin_amdgcn_readlane(s_l, c);
            float w0 = rl_f(w_l, c);
            unsigned short u0 = *((const unsigned short*)(hq + (size_t)sp0 * 128) + lane);
            f32x2 wv0 = {w0, w0};
            acc2 += wv0 * __builtin_amdgcn_cvt_pk_f32_fp8((int)u0, false);
        }
    }
    float v0 = acc2.x + bias[lane * 2];
    float v1 = acc2.y + bias[lane * 2 + 1];
    v0 = v0 > 0.f ? v0 : (__expf(v0) - 1.f);
    v1 = v1 > 0.f ? v1 : (__expf(v1) - 1.f);
    float2 pv = {v0, v1};
    *(float2*)&out[(size_t)n * 128 + lane * 2] = pv;
}

// ---------------- mean pool + final GEMV (fused via done-counter) -------------
__global__ __launch_bounds__(256) void pool_final_kernel(const float* __restrict__ o2,
                                                         float* __restrict__ pool,
                                                         int* __restrict__ done,
                                                         const float* __restrict__ Wout,
                                                         const float* __restrict__ bout,
                                                         float* __restrict__ out,
                                                         int N, int nblocks, float invN) {
    __shared__ float4 sred[256];
    int f4 = threadIdx.x & 31;
    int r = blockIdx.x * 256 + (threadIdx.x >> 5);
    float4 acc = {0.f, 0.f, 0.f, 0.f};
    for (int i = 0; i < 32; i++, r += 8) {
        if (r < N) {
            float4 v = *(const float4*)&o2[(size_t)r * 128 + f4 * 4];
            acc.x += v.x; acc.y += v.y; acc.z += v.z; acc.w += v.w;
        }
    }
    sred[threadIdx.x] = acc;
    __syncthreads();
    if (threadIdx.x < 32) {
        float4 t = sred[threadIdx.x];
#pragma unroll
        for (int k = 1; k < 8; k++) {
            float4 u = sred[threadIdx.x + 32 * k];
            t.x += u.x; t.y += u.y; t.z += u.z; t.w += u.w;
        }
        atomicAdd(&pool[f4 * 4 + 0], t.x);
        atomicAdd(&pool[f4 * 4 + 1], t.y);
        atomicAdd(&pool[f4 * 4 + 2], t.z);
        atomicAdd(&pool[f4 * 4 + 3], t.w);
    }
    __threadfence();
    __shared__ int isLast;
    if (threadIdx.x == 0) isLast = (atomicAdd(done, 1) == nblocks - 1);
    __syncthreads();
    if (isLast) {
        __shared__ float spool[128];
        if (threadIdx.x < 128) spool[threadIdx.x] = atomicAdd(&pool[threadIdx.x], 0.f);
        __syncthreads();
        int o = threadIdx.x;
        float a = 0.f;
        for (int k = 0; k < 128; k++) a += spool[k] * Wout[k * 256 + o];
        out[o] = a * invN + bout[o];
    }
}

// ---------------- launch ------------------------------------------------------
extern "C" void kernel_launch(void* const* d_in, const int* in_sizes, int n_in,
                              void* d_out, int out_size, void* d_ws, size_t ws_size,
                              hipStream_t stream) {
    const float* x      = (const float*)d_in[0];
    const int*   ei     = (const int*)d_in[1];
    const float* W_emb  = (const float*)d_in[2];
    const float* b_emb  = (const float*)d_in[3];
    const float* W1     = (const float*)d_in[4];
    const float* a1_src = (const float*)d_in[5];
    const float* a1_dst = (const float*)d_in[6];
    const float* b1     = (const float*)d_in[7];
    const float* W2     = (const float*)d_in[8];
    const float* a2_src = (const float*)d_in[9];
    const float* a2_dst = (const float*)d_in[10];
    const float* b2     = (const float*)d_in[11];
    const float* W_out  = (const float*)d_in[12];
    const float* b_out  = (const float*)d_in[13];
    float* out = (float*)d_out;

    const int N = in_sizes[0] / 64;   // 25000
    const int E = in_sizes[1] / 2;    // 400000
    const int Etot = E + N;
    const int nb = (N + 255) / 256;   // 98 blocks — must stay <= CU count (lookback co-residency)
    const int mtiles = (N + 127) / 128;   // 196
    const int nrb = mtiles * 8;           // 16-row fragment blocks incl. tail

    char* ws = (char*)d_ws;
    size_t off = 0;
    auto alloc = [&](size_t bytes) -> void* {
        void* p = ws + off;
        off = (off + bytes + 255) & ~(size_t)255;
        return p;
    };
    typedef unsigned short u16;
    u16* xbS   = (u16*)alloc((size_t)nrb * 1024 * 2);     // frag-swizzled x (bf16)
    u16* WeS   = (u16*)alloc((size_t)8 * 1024 * 2);       // frag-swizzled We
    u16* W1S   = (u16*)alloc((size_t)32 * 2048 * 2);      // frag-swizzled W1
    u16* W2T   = (u16*)alloc((size_t)128 * 512 * 2);
    unsigned char* h1q = (unsigned char*)alloc((size_t)N * 512);   // fp8
    u16* o1b   = (u16*)alloc((size_t)N * 512 * 2);
    unsigned char* h2q = (unsigned char*)alloc((size_t)N * 128);   // fp8
    float* o2  = (float*)alloc((size_t)N * 128 * 4);
    float* as1 = (float*)alloc((size_t)N * 4 * 4);
    float* ad1 = (float*)alloc((size_t)N * 4 * 4);
    float* as2 = (float*)alloc((size_t)N * 4);
    float* ad2 = (float*)alloc((size_t)N * 4);
    float* pool = (float*)alloc(128 * 4);
    int* done   = (int*)alloc(256);
    int* rowptr = (int*)alloc((size_t)(N + 1) * 4);
    int* deg    = (int*)alloc((size_t)N * 4);
    int* cursor = (int*)alloc((size_t)N * 4);
    int* sagg   = (int*)alloc((size_t)nb * 4);
    int* sflg   = (int*)alloc((size_t)nb * 4);
    int* esrc   = (int*)alloc((size_t)Etot * 4);

    const int blocksE = (Etot + 255) / 256;
    const int Nx = N * 64;
    const int prepElems = Nx + 64 * 128 + 128 * 512 + 512 * 128;
    const int prepBlocks = (prepElems + 255) / 256;

    // K1: zero deg/pool/done + scan flags & aggs
    int zn = N + 128 + 1 + 2 * nb;
    zero_kernel<<<(zn + 255) / 256, 256, 0, stream>>>(deg, pool, done, sflg, sagg, N, nb);

    // K2: degree histogram (atomics) ∥ swizzled bf16 conversions
    degcount_prep<<<blocksE + prepBlocks, 256, 0, stream>>>(ei, E, N, deg, blocksE,
                                                            x, W_emb, W1, W2,
                                                            xbS, WeS, W1S, W2T, Nx);

    // K3: single-dispatch exclusive scan (decoupled lookback) + cursor seed
    scan_lookback<<<nb, 256, 0, stream>>>(deg, rowptr, cursor, sagg, sflg, N, nb);

    // K4: CSR scatter (tiny, full occupancy)
    scatter_kernel<<<blocksE, 256, 0, stream>>>(ei, E, N, cursor, esrc);

    // K5: fused GEMM1+2 (h1pre = relu(x@We+be)@W1, fp8 + alpha1), r13 struct
    gemm12_fused<<<dim3(4, mtiles), 256, 0, stream>>>(xbS, WeS, b_emb, W1S, h1q,
                                                      a1_src, a1_dst, as1, ad1, N);

    // K6: layer-1 aggregation (logits on the fly, fp8 gather)
    gat_agg_l1<<<(N + 3) / 4, 256, 0, stream>>>((const unsigned*)h1q, (const float4*)as1,
                                                (const float4*)ad1, rowptr, esrc, b1, o1b, N);

    // K7: h2pre = o1 @ W2  [N,128] fp8 + fused alpha2 (r19: reg double-buffer)
    gemm_mfma_nt<0, 1, 1, 1><<<dim3(1, mtiles), 256, 0, stream>>>(
        o1b, W2T, nullptr, h2q, a2_src, a2_dst, as2, ad2, N, 128, 512);

    // K8: layer-2 aggregation
    gat_agg_l2<<<(N + 3) / 4, 256, 0, stream>>>(h2q, as2, ad2, rowptr, esrc, b2, o2, N);

    // K9: mean pool + final GEMV
    int npb = (N + 255) / 256;
    pool_final_kernel<<<npb, 256, 0, stream>>>(o2, pool, done, W_out, b_out, out,
                                               N, npb, 1.f / (float)N);
}